// Round 1
// baseline (4788.745 us; speedup 1.0000x reference)
//
#include <hip/hip_runtime.h>
#include <math.h>

#define NN 4096      // nodes per graph
#define EE 65536     // edges per graph
#define NS 8192      // stacked nodes (2 graphs)
#define NFEAT 1280
#define NHID 512
#define DFF 2048

// workspace offsets (in floats)
static const unsigned long long OFF_SCALED = 0ull;          // 8192*1280 = 10,485,760
static const unsigned long long OFF_HPRE   = 10485760ull;   // 8192*512  =  4,194,304
static const unsigned long long OFF_X      = 14680064ull;   // 8192*512
static const unsigned long long OFF_QKV    = 18874368ull;   // 8192*2048 = 16,777,216 (qkv then ff1out)
static const unsigned long long OFF_CTX    = 35651584ull;   // 8192*512
static const unsigned long long OFF_MEANS  = 39845888ull;   // 2*16*512 = 16,384
static const unsigned long long OFF_DEG    = 39862272ull;   // 4*4096   = 16,384
// total = 39,878,656 floats = 152.1 MiB

// ---------------- degree kernels ----------------
__global__ __launch_bounds__(256) void k_deg_count(const int* __restrict__ s1, const int* __restrict__ d1,
                                                   const int* __restrict__ s2, const int* __restrict__ d2,
                                                   float* __restrict__ deg)
{
    int e = blockIdx.x * 256 + threadIdx.x;
    if (e < EE) {
        atomicAdd(&deg[s1[e]], 1.0f);
        atomicAdd(&deg[NN + d1[e]], 1.0f);
        atomicAdd(&deg[2 * NN + s2[e]], 1.0f);
        atomicAdd(&deg[3 * NN + d2[e]], 1.0f);
    }
}

__global__ __launch_bounds__(256) void k_deg_fin(float* __restrict__ deg)
{
    int i = blockIdx.x * 256 + threadIdx.x;
    if (i < 4 * NN) deg[i] = rsqrtf(fmaxf(deg[i], 1.0f));
}

// ---------------- row scale: out[r] = in[r] * sc[r] (stacked 2-graph) ----------------
__global__ __launch_bounds__(256) void k_scale_rows(const float* __restrict__ in1, const float* __restrict__ in2,
                                                    const float* __restrict__ sc1, const float* __restrict__ sc2,
                                                    float* __restrict__ out, int ncol)
{
    int quads = ncol >> 2;
    long long idx = (long long)blockIdx.x * 256 + threadIdx.x;
    if (idx >= (long long)NS * quads) return;
    int r  = (int)(idx / quads);
    int cq = (int)(idx % quads) * 4;
    const float* in; const float* sc; int rr;
    if (r < NN) { in = in1; sc = sc1; rr = r; } else { in = in2; sc = sc2; rr = r - NN; }
    float4 v = *(const float4*)&in[(size_t)rr * ncol + cq];
    float s = sc[rr];
    v.x *= s; v.y *= s; v.z *= s; v.w *= s;
    *(float4*)&out[(size_t)r * ncol + cq] = v;
}

// ---------------- GEMM: C[M,N] = A[M,K] @ W[N,K]^T (+bias)(+relu) ----------------
#define BM 128
#define BN 128
#define BK 8
__global__ __launch_bounds__(256) void k_gemm(const float* __restrict__ A, const float* __restrict__ W,
                                              const float* __restrict__ bias, float* __restrict__ C,
                                              int M, int N, int K, int relu)
{
    __shared__ float As[BK][BM + 4];
    __shared__ float Ws[BK][BN + 4];
    int tid = threadIdx.x;
    int tx = tid & 15, ty = tid >> 4;
    int row0 = blockIdx.y * BM, col0 = blockIdx.x * BN;
    float acc[8][8];
#pragma unroll
    for (int i = 0; i < 8; ++i)
#pragma unroll
        for (int j = 0; j < 8; ++j) acc[i][j] = 0.0f;

    int lr = tid >> 1, lq = (tid & 1) * 4;
    for (int k0 = 0; k0 < K; k0 += BK) {
        float4 av = *(const float4*)&A[(size_t)(row0 + lr) * K + k0 + lq];
        float4 wv = *(const float4*)&W[(size_t)(col0 + lr) * K + k0 + lq];
        As[lq + 0][lr] = av.x; As[lq + 1][lr] = av.y; As[lq + 2][lr] = av.z; As[lq + 3][lr] = av.w;
        Ws[lq + 0][lr] = wv.x; Ws[lq + 1][lr] = wv.y; Ws[lq + 2][lr] = wv.z; Ws[lq + 3][lr] = wv.w;
        __syncthreads();
#pragma unroll
        for (int kk = 0; kk < BK; ++kk) {
            float4 a0 = *(const float4*)&As[kk][ty * 8];
            float4 a1 = *(const float4*)&As[kk][ty * 8 + 4];
            float4 b0 = *(const float4*)&Ws[kk][tx * 8];
            float4 b1 = *(const float4*)&Ws[kk][tx * 8 + 4];
            float a[8] = {a0.x, a0.y, a0.z, a0.w, a1.x, a1.y, a1.z, a1.w};
            float b[8] = {b0.x, b0.y, b0.z, b0.w, b1.x, b1.y, b1.z, b1.w};
#pragma unroll
            for (int i = 0; i < 8; ++i)
#pragma unroll
                for (int j = 0; j < 8; ++j)
                    acc[i][j] = fmaf(a[i], b[j], acc[i][j]);
        }
        __syncthreads();
    }
#pragma unroll
    for (int i = 0; i < 8; ++i) {
        size_t r = (size_t)row0 + ty * 8 + i;
#pragma unroll
        for (int j = 0; j < 8; j += 4) {
            int c = col0 + tx * 8 + j;
            float4 v;
            v.x = acc[i][j]; v.y = acc[i][j + 1]; v.z = acc[i][j + 2]; v.w = acc[i][j + 3];
            if (bias) { v.x += bias[c]; v.y += bias[c + 1]; v.z += bias[c + 2]; v.w += bias[c + 3]; }
            if (relu) { v.x = fmaxf(v.x, 0.f); v.y = fmaxf(v.y, 0.f); v.z = fmaxf(v.z, 0.f); v.w = fmaxf(v.w, 0.f); }
            *(float4*)&C[r * N + c] = v;
        }
    }
}

// ---------------- edge scatter-add: agg[dst] += h[src], both stacked graphs ----------------
__global__ __launch_bounds__(256) void k_scatter(const float* __restrict__ h, float* __restrict__ agg,
                                                 const int* __restrict__ s1, const int* __restrict__ d1,
                                                 const int* __restrict__ s2, const int* __restrict__ d2)
{
    int e = blockIdx.x;   // 0 .. 2*EE-1
    int c = threadIdx.x;  // 0..255
    int s, d, off;
    if (e < EE) { s = s1[e]; d = d1[e]; off = 0; }
    else        { s = s2[e - EE]; d = d2[e - EE]; off = NN; }
    const float* hp = &h[(size_t)(off + s) * NHID];
    float* ap = &agg[(size_t)(off + d) * NHID];
    atomicAdd(&ap[c], hp[c]);
    atomicAdd(&ap[c + 256], hp[c + 256]);
}

// ---------------- GC finalize: x = relu(agg * dinv_in[r] + b[c]) in place ----------------
__global__ __launch_bounds__(256) void k_gcfin(float* __restrict__ agg, const float* __restrict__ sc1,
                                               const float* __restrict__ sc2, const float* __restrict__ bias)
{
    size_t idx = (size_t)blockIdx.x * 256 + threadIdx.x;  // over NS*128 quads
    int r  = (int)(idx >> 7);
    int cq = (int)(idx & 127) * 4;
    float s = (r < NN) ? sc1[r] : sc2[r - NN];
    float4 v = *(float4*)&agg[(size_t)r * NHID + cq];
    float4 b = *(const float4*)&bias[cq];
    v.x = fmaxf(fmaf(v.x, s, b.x), 0.f);
    v.y = fmaxf(fmaf(v.y, s, b.y), 0.f);
    v.z = fmaxf(fmaf(v.z, s, b.z), 0.f);
    v.w = fmaxf(fmaf(v.w, s, b.w), 0.f);
    *(float4*)&agg[(size_t)r * NHID + cq] = v;
}

// ---------------- flash attention (fp32, 1 query per lane, 64x64 K/V tiles) ----------------
__global__ __launch_bounds__(64) void k_flash(const float* __restrict__ qkv, float* __restrict__ ctx)
{
    __shared__ float Kt[64][68];
    __shared__ float Vt[64][68];
    int lane = threadIdx.x;
    int qt = blockIdx.x, h = blockIdx.y, g = blockIdx.z;
    size_t base = (size_t)g * NN;
    int qrow = qt * 64 + lane;
    const float* qp = &qkv[(base + qrow) * 1536 + h * 64];
    float q[64], o[64];
#pragma unroll
    for (int d4 = 0; d4 < 64; d4 += 4) {
        float4 v = *(const float4*)&qp[d4];
        q[d4] = v.x * 0.125f; q[d4 + 1] = v.y * 0.125f; q[d4 + 2] = v.z * 0.125f; q[d4 + 3] = v.w * 0.125f;
    }
#pragma unroll
    for (int d = 0; d < 64; ++d) o[d] = 0.0f;
    float m = -1e30f, l = 0.0f;

    for (int t0 = 0; t0 < NN; t0 += 64) {
        const float* kp = &qkv[(base + t0 + lane) * 1536 + 512 + h * 64];
        const float* vp = kp + 512;
#pragma unroll
        for (int d4 = 0; d4 < 64; d4 += 4) {
            float4 kv = *(const float4*)&kp[d4];
            Kt[lane][d4] = kv.x; Kt[lane][d4 + 1] = kv.y; Kt[lane][d4 + 2] = kv.z; Kt[lane][d4 + 3] = kv.w;
            float4 vv = *(const float4*)&vp[d4];
            Vt[lane][d4] = vv.x; Vt[lane][d4 + 1] = vv.y; Vt[lane][d4 + 2] = vv.z; Vt[lane][d4 + 3] = vv.w;
        }
        __syncthreads();
#pragma unroll 1
        for (int j = 0; j < 64; ++j) {
            float s = 0.0f;
#pragma unroll
            for (int d4 = 0; d4 < 64; d4 += 4) {
                float4 kv = *(const float4*)&Kt[j][d4];
                s = fmaf(q[d4], kv.x, s);
                s = fmaf(q[d4 + 1], kv.y, s);
                s = fmaf(q[d4 + 2], kv.z, s);
                s = fmaf(q[d4 + 3], kv.w, s);
            }
            if (s > m) {
                float corr = __expf(m - s);
                l *= corr;
#pragma unroll
                for (int d = 0; d < 64; ++d) o[d] *= corr;
                m = s;
            }
            float p = __expf(s - m);
            l += p;
#pragma unroll
            for (int d4 = 0; d4 < 64; d4 += 4) {
                float4 vv = *(const float4*)&Vt[j][d4];
                o[d4]     = fmaf(p, vv.x, o[d4]);
                o[d4 + 1] = fmaf(p, vv.y, o[d4 + 1]);
                o[d4 + 2] = fmaf(p, vv.z, o[d4 + 2]);
                o[d4 + 3] = fmaf(p, vv.w, o[d4 + 3]);
            }
        }
        __syncthreads();
    }
    float inv = 1.0f / l;
    float* op = &ctx[(base + qrow) * NHID + h * 64];
#pragma unroll
    for (int d4 = 0; d4 < 64; d4 += 4) {
        float4 v;
        v.x = o[d4] * inv; v.y = o[d4 + 1] * inv; v.z = o[d4 + 2] * inv; v.w = o[d4 + 3] * inv;
        *(float4*)&op[d4] = v;
    }
}

// ---------------- fused residual-add + LayerNorm (512 cols, in place on x) ----------------
__global__ __launch_bounds__(256) void k_add_ln(float* __restrict__ x, const float* __restrict__ y,
                                                const float* __restrict__ g, const float* __restrict__ bb)
{
    int r = blockIdx.x, tid = threadIdx.x;
    int c = tid * 2;
    float2 xv = *(float2*)&x[(size_t)r * NHID + c];
    float2 yv = *(const float2*)&y[(size_t)r * NHID + c];
    float a0 = xv.x + yv.x, a1 = xv.y + yv.y;
    float s = a0 + a1;
    float qs = a0 * a0 + a1 * a1;
#pragma unroll
    for (int off = 32; off > 0; off >>= 1) {
        s  += __shfl_xor(s, off);
        qs += __shfl_xor(qs, off);
    }
    __shared__ float ss[4], qq[4];
    int w = tid >> 6;
    if ((tid & 63) == 0) { ss[w] = s; qq[w] = qs; }
    __syncthreads();
    s  = ss[0] + ss[1] + ss[2] + ss[3];
    qs = qq[0] + qq[1] + qq[2] + qq[3];
    float mu  = s * (1.0f / NHID);
    float var = qs * (1.0f / NHID) - mu * mu;
    float rs = rsqrtf(var + 1e-5f);
    float2 gv = *(const float2*)&g[c];
    float2 bv = *(const float2*)&bb[c];
    float o0 = (a0 - mu) * rs * gv.x + bv.x;
    float o1 = (a1 - mu) * rs * gv.y + bv.y;
    *(float2*)&x[(size_t)r * NHID + c] = make_float2(o0, o1);
}

// ---------------- per-segment mean (16 segments x 2 stacks) ----------------
__global__ __launch_bounds__(512) void k_seg_mean(const float* __restrict__ h, const int* __restrict__ seg1,
                                                  const int* __restrict__ seg2, float* __restrict__ means)
{
    int b = blockIdx.x;     // 0..15
    int st = blockIdx.y;    // 0..1
    int col = threadIdx.x;  // 0..511
    const int* seg = (st == 0) ? seg1 : seg2;
    float acc = 0.0f, cnt = 0.0f;
    for (int i = 0; i < NN; ++i) {
        if (seg[i] == b) { acc += h[((size_t)st * NN + i) * NHID + col]; cnt += 1.0f; }
    }
    means[((size_t)st * 16 + b) * NHID + col] = acc / fmaxf(cnt, 1.0f);
}

// ---------------- MLP head + softmax (single block) ----------------
__global__ __launch_bounds__(512) void k_head(const float* __restrict__ means,
                                              const float* __restrict__ l1w, const float* __restrict__ l1b,
                                              const float* __restrict__ l2w, const float* __restrict__ l2b,
                                              const float* __restrict__ l3w, const float* __restrict__ l3b,
                                              float* __restrict__ out)
{
    __shared__ float hg[16][512];
    __shared__ float t2[16][128];
    int tid = threadIdx.x;
#pragma unroll
    for (int sgm = 0; sgm < 16; ++sgm)
        hg[sgm][tid] = means[sgm * 512 + tid] * means[(16 + sgm) * 512 + tid];
    __syncthreads();
    float rbuf[16];
#pragma unroll
    for (int sgm = 0; sgm < 16; ++sgm) {
        float acc = l1b[tid];
        for (int k = 0; k < 512; ++k) acc = fmaf(hg[sgm][k], l1w[(size_t)tid * 512 + k], acc);
        rbuf[sgm] = acc;
    }
    __syncthreads();
#pragma unroll
    for (int sgm = 0; sgm < 16; ++sgm) hg[sgm][tid] = rbuf[sgm];
    __syncthreads();
    for (int i = tid; i < 16 * 128; i += 512) {
        int bb = i >> 7, n = i & 127;
        float acc = l2b[n];
        for (int k = 0; k < 512; ++k) acc = fmaf(hg[bb][k], l2w[(size_t)n * 512 + k], acc);
        t2[bb][n] = acc;
    }
    __syncthreads();
    if (tid < 16) {
        float v0 = l3b[0], v1 = l3b[1];
        for (int k = 0; k < 128; ++k) {
            float t = t2[tid][k];
            v0 = fmaf(t, l3w[k], v0);
            v1 = fmaf(t, l3w[128 + k], v1);
        }
        float mx = fmaxf(v0, v1);
        float e0 = __expf(v0 - mx), e1 = __expf(v1 - mx);
        float inv = 1.0f / (e0 + e1);
        out[tid * 2 + 0] = e0 * inv;
        out[tid * 2 + 1] = e1 * inv;
    }
}

// ---------------- launch ----------------
extern "C" void kernel_launch(void* const* d_in, const int* in_sizes, int n_in,
                              void* d_out, int out_size, void* d_ws, size_t ws_size,
                              hipStream_t stream)
{
    const float* fea1 = (const float*)d_in[0];
    const float* fea2 = (const float*)d_in[1];
    const int* src1 = (const int*)d_in[2];
    const int* dst1 = (const int*)d_in[3];
    const int* src2 = (const int*)d_in[4];
    const int* dst2 = (const int*)d_in[5];
    const int* seg1 = (const int*)d_in[6];
    const int* seg2 = (const int*)d_in[7];
    const float* W1 = (const float*)d_in[9];
    const float* b1 = (const float*)d_in[10];
    const float* W2 = (const float*)d_in[11];
    const float* b2 = (const float*)d_in[12];
    const float* in_proj_w = (const float*)d_in[13];
    const float* in_proj_b = (const float*)d_in[14];
    const float* out_proj_w = (const float*)d_in[15];
    const float* out_proj_b = (const float*)d_in[16];
    const float* ln1_g = (const float*)d_in[17];
    const float* ln1_b = (const float*)d_in[18];
    const float* ln2_g = (const float*)d_in[19];
    const float* ln2_b = (const float*)d_in[20];
    const float* ff1_w = (const float*)d_in[21];
    const float* ff1_b = (const float*)d_in[22];
    const float* ff2_w = (const float*)d_in[23];
    const float* ff2_b = (const float*)d_in[24];
    const float* l1_w = (const float*)d_in[25];
    const float* l1_b = (const float*)d_in[26];
    const float* l2_w = (const float*)d_in[27];
    const float* l2_b = (const float*)d_in[28];
    const float* l3_w = (const float*)d_in[29];
    const float* l3_b = (const float*)d_in[30];

    float* ws = (float*)d_ws;
    float* SC = ws + OFF_SCALED;
    float* HP = ws + OFF_HPRE;
    float* X  = ws + OFF_X;
    float* QK = ws + OFF_QKV;
    float* CT = ws + OFF_CTX;
    float* ME = ws + OFF_MEANS;
    float* DG = ws + OFF_DEG;
    float* dout1 = DG;
    float* din1  = DG + NN;
    float* dout2 = DG + 2 * NN;
    float* din2  = DG + 3 * NN;

    // zero degree counters and GC1 agg target (ws is poisoned each call)
    hipMemsetAsync(DG, 0, 4 * NN * sizeof(float), stream);
    hipMemsetAsync(X, 0, (size_t)NS * NHID * sizeof(float), stream);

    // degrees
    k_deg_count<<<EE / 256, 256, 0, stream>>>(src1, dst1, src2, dst2, DG);
    k_deg_fin<<<(4 * NN) / 256, 256, 0, stream>>>(DG);

    // GC1: scale -> gemm W1 -> scatter -> finalize(relu)
    {
        long long tq = (long long)NS * (NFEAT / 4);
        k_scale_rows<<<(int)((tq + 255) / 256), 256, 0, stream>>>(fea1, fea2, dout1, dout2, SC, NFEAT);
    }
    k_gemm<<<dim3(NHID / BN, NS / BM), 256, 0, stream>>>(SC, W1, nullptr, HP, NS, NHID, NFEAT, 0);
    k_scatter<<<2 * EE, 256, 0, stream>>>(HP, X, src1, dst1, src2, dst2);
    k_gcfin<<<(NS * 128) / 256, 256, 0, stream>>>(X, din1, din2, b1);

    // encoder: qkv -> attention -> out_proj -> LN1 -> FF -> LN2
    k_gemm<<<dim3(1536 / BN, NS / BM), 256, 0, stream>>>(X, in_proj_w, in_proj_b, QK, NS, 1536, NHID, 0);
    k_flash<<<dim3(NN / 64, 8, 2), 64, 0, stream>>>(QK, CT);
    k_gemm<<<dim3(NHID / BN, NS / BM), 256, 0, stream>>>(CT, out_proj_w, out_proj_b, HP, NS, NHID, NHID, 0);
    k_add_ln<<<NS, 256, 0, stream>>>(X, HP, ln1_g, ln1_b);
    k_gemm<<<dim3(DFF / BN, NS / BM), 256, 0, stream>>>(X, ff1_w, ff1_b, QK, NS, DFF, NHID, 1);
    k_gemm<<<dim3(NHID / BN, NS / BM), 256, 0, stream>>>(QK, ff2_w, ff2_b, HP, NS, NHID, DFF, 0);
    k_add_ln<<<NS, 256, 0, stream>>>(X, HP, ln2_g, ln2_b);

    // GC2
    {
        long long tq = (long long)NS * (NHID / 4);
        k_scale_rows<<<(int)((tq + 255) / 256), 256, 0, stream>>>(X, X + (size_t)NN * NHID, dout1, dout2, SC, NHID);
    }
    k_gemm<<<dim3(NHID / BN, NS / BM), 256, 0, stream>>>(SC, W2, nullptr, HP, NS, NHID, NHID, 0);
    hipMemsetAsync(CT, 0, (size_t)NS * NHID * sizeof(float), stream);
    k_scatter<<<2 * EE, 256, 0, stream>>>(HP, CT, src1, dst1, src2, dst2);
    k_gcfin<<<(NS * 128) / 256, 256, 0, stream>>>(CT, din1, din2, b2);

    // readout
    k_seg_mean<<<dim3(16, 2), 512, 0, stream>>>(CT, seg1, seg2, ME);
    k_head<<<1, 512, 0, stream>>>(ME, l1_w, l1_b, l2_w, l2_b, l3_w, l3_b, (float*)d_out);
}

// Round 2
// 4306.675 us; speedup vs baseline: 1.1119x; 1.1119x over previous
//
#include <hip/hip_runtime.h>
#include <math.h>

#define NN 4096      // nodes per graph
#define EE 65536     // edges per graph
#define NS 8192      // stacked nodes (2 graphs)
#define NFEAT 1280
#define NHID 512
#define DFF 2048

// workspace offsets (in floats)
static const unsigned long long OFF_SCALED = 0ull;          // 8192*1280 = 10,485,760
static const unsigned long long OFF_HPRE   = 10485760ull;   // 8192*512  =  4,194,304
static const unsigned long long OFF_X      = 14680064ull;   // 8192*512
static const unsigned long long OFF_QKV    = 18874368ull;   // 8192*2048 = 16,777,216 (qkv then ff1out)
static const unsigned long long OFF_CTX    = 35651584ull;   // 8192*512
static const unsigned long long OFF_MEANS  = 39845888ull;   // 2*16*512 = 16,384
static const unsigned long long OFF_DEG    = 39862272ull;   // 4*4096   = 16,384
// total = 39,878,656 floats = 152.1 MiB
// During attention, SC (10.49M floats) holds bf16 partial O (needs 16.78M bf16 = 8.39M float slots)
// and HP (4.19M floats) holds partial (m,l) float2 (needs 0.26M floats).

// ---------------- degree kernels ----------------
__global__ __launch_bounds__(256) void k_deg_count(const int* __restrict__ s1, const int* __restrict__ d1,
                                                   const int* __restrict__ s2, const int* __restrict__ d2,
                                                   float* __restrict__ deg)
{
    int e = blockIdx.x * 256 + threadIdx.x;
    if (e < EE) {
        atomicAdd(&deg[s1[e]], 1.0f);
        atomicAdd(&deg[NN + d1[e]], 1.0f);
        atomicAdd(&deg[2 * NN + s2[e]], 1.0f);
        atomicAdd(&deg[3 * NN + d2[e]], 1.0f);
    }
}

__global__ __launch_bounds__(256) void k_deg_fin(float* __restrict__ deg)
{
    int i = blockIdx.x * 256 + threadIdx.x;
    if (i < 4 * NN) deg[i] = rsqrtf(fmaxf(deg[i], 1.0f));
}

// ---------------- row scale: out[r] = in[r] * sc[r] (stacked 2-graph) ----------------
__global__ __launch_bounds__(256) void k_scale_rows(const float* __restrict__ in1, const float* __restrict__ in2,
                                                    const float* __restrict__ sc1, const float* __restrict__ sc2,
                                                    float* __restrict__ out, int ncol)
{
    int quads = ncol >> 2;
    long long idx = (long long)blockIdx.x * 256 + threadIdx.x;
    if (idx >= (long long)NS * quads) return;
    int r  = (int)(idx / quads);
    int cq = (int)(idx % quads) * 4;
    const float* in; const float* sc; int rr;
    if (r < NN) { in = in1; sc = sc1; rr = r; } else { in = in2; sc = sc2; rr = r - NN; }
    float4 v = *(const float4*)&in[(size_t)rr * ncol + cq];
    float s = sc[rr];
    v.x *= s; v.y *= s; v.z *= s; v.w *= s;
    *(float4*)&out[(size_t)r * ncol + cq] = v;
}

// ---------------- GEMM: C[M,N] = A[M,K] @ W[N,K]^T (+bias)(+relu) ----------------
#define BM 128
#define BN 128
#define BK 8
__global__ __launch_bounds__(256) void k_gemm(const float* __restrict__ A, const float* __restrict__ W,
                                              const float* __restrict__ bias, float* __restrict__ C,
                                              int M, int N, int K, int relu)
{
    __shared__ float As[BK][BM + 4];
    __shared__ float Ws[BK][BN + 4];
    int tid = threadIdx.x;
    int tx = tid & 15, ty = tid >> 4;
    int row0 = blockIdx.y * BM, col0 = blockIdx.x * BN;
    float acc[8][8];
#pragma unroll
    for (int i = 0; i < 8; ++i)
#pragma unroll
        for (int j = 0; j < 8; ++j) acc[i][j] = 0.0f;

    int lr = tid >> 1, lq = (tid & 1) * 4;
    for (int k0 = 0; k0 < K; k0 += BK) {
        float4 av = *(const float4*)&A[(size_t)(row0 + lr) * K + k0 + lq];
        float4 wv = *(const float4*)&W[(size_t)(col0 + lr) * K + k0 + lq];
        As[lq + 0][lr] = av.x; As[lq + 1][lr] = av.y; As[lq + 2][lr] = av.z; As[lq + 3][lr] = av.w;
        Ws[lq + 0][lr] = wv.x; Ws[lq + 1][lr] = wv.y; Ws[lq + 2][lr] = wv.z; Ws[lq + 3][lr] = wv.w;
        __syncthreads();
#pragma unroll
        for (int kk = 0; kk < BK; ++kk) {
            float4 a0 = *(const float4*)&As[kk][ty * 8];
            float4 a1 = *(const float4*)&As[kk][ty * 8 + 4];
            float4 b0 = *(const float4*)&Ws[kk][tx * 8];
            float4 b1 = *(const float4*)&Ws[kk][tx * 8 + 4];
            float a[8] = {a0.x, a0.y, a0.z, a0.w, a1.x, a1.y, a1.z, a1.w};
            float b[8] = {b0.x, b0.y, b0.z, b0.w, b1.x, b1.y, b1.z, b1.w};
#pragma unroll
            for (int i = 0; i < 8; ++i)
#pragma unroll
                for (int j = 0; j < 8; ++j)
                    acc[i][j] = fmaf(a[i], b[j], acc[i][j]);
        }
        __syncthreads();
    }
#pragma unroll
    for (int i = 0; i < 8; ++i) {
        size_t r = (size_t)row0 + ty * 8 + i;
#pragma unroll
        for (int j = 0; j < 8; j += 4) {
            int c = col0 + tx * 8 + j;
            float4 v;
            v.x = acc[i][j]; v.y = acc[i][j + 1]; v.z = acc[i][j + 2]; v.w = acc[i][j + 3];
            if (bias) { v.x += bias[c]; v.y += bias[c + 1]; v.z += bias[c + 2]; v.w += bias[c + 3]; }
            if (relu) { v.x = fmaxf(v.x, 0.f); v.y = fmaxf(v.y, 0.f); v.z = fmaxf(v.z, 0.f); v.w = fmaxf(v.w, 0.f); }
            *(float4*)&C[r * N + c] = v;
        }
    }
}

// ---------------- edge scatter-add: agg[dst] += h[src], both stacked graphs ----------------
__global__ __launch_bounds__(256) void k_scatter(const float* __restrict__ h, float* __restrict__ agg,
                                                 const int* __restrict__ s1, const int* __restrict__ d1,
                                                 const int* __restrict__ s2, const int* __restrict__ d2)
{
    int e = blockIdx.x;   // 0 .. 2*EE-1
    int c = threadIdx.x;  // 0..255
    int s, d, off;
    if (e < EE) { s = s1[e]; d = d1[e]; off = 0; }
    else        { s = s2[e - EE]; d = d2[e - EE]; off = NN; }
    const float* hp = &h[(size_t)(off + s) * NHID];
    float* ap = &agg[(size_t)(off + d) * NHID];
    atomicAdd(&ap[c], hp[c]);
    atomicAdd(&ap[c + 256], hp[c + 256]);
}

// ---------------- GC finalize: x = relu(agg * dinv_in[r] + b[c]) in place ----------------
__global__ __launch_bounds__(256) void k_gcfin(float* __restrict__ agg, const float* __restrict__ sc1,
                                               const float* __restrict__ sc2, const float* __restrict__ bias)
{
    size_t idx = (size_t)blockIdx.x * 256 + threadIdx.x;  // over NS*128 quads
    int r  = (int)(idx >> 7);
    int cq = (int)(idx & 127) * 4;
    float s = (r < NN) ? sc1[r] : sc2[r - NN];
    float4 v = *(float4*)&agg[(size_t)r * NHID + cq];
    float4 b = *(const float4*)&bias[cq];
    v.x = fmaxf(fmaf(v.x, s, b.x), 0.f);
    v.y = fmaxf(fmaf(v.y, s, b.y), 0.f);
    v.z = fmaxf(fmaf(v.z, s, b.z), 0.f);
    v.w = fmaxf(fmaf(v.w, s, b.w), 0.f);
    *(float4*)&agg[(size_t)r * NHID + cq] = v;
}

// bf16 pack/unpack helpers (RNE)
__device__ __forceinline__ unsigned int pack_bf16_2(float a, float b)
{
    unsigned int ua = __float_as_uint(a);
    unsigned int ub = __float_as_uint(b);
    ua = (ua + 0x7fffu + ((ua >> 16) & 1u)) >> 16;
    ub = (ub + 0x7fffu + ((ub >> 16) & 1u)) >> 16;
    return ua | (ub << 16);
}
__device__ __forceinline__ float bf16_lo(unsigned int u) { return __uint_as_float(u << 16); }
__device__ __forceinline__ float bf16_hi(unsigned int u) { return __uint_as_float(u & 0xffff0000u); }

// ---------------- flash attention v2 ----------------
// 1 wave / block; 32 queries per wave (lane pair splits the 64-dim head);
// 16-row fp32 K/V tiles in LDS; split-KV x2 with bf16 partial O + fp32 (m,l).
#define KV_TILE 16
#define NCHUNK 2
#define CHUNK_KEYS (NN / NCHUNK)
__global__ __launch_bounds__(64) void k_flash2(const float* __restrict__ qkv,
                                               unsigned int* __restrict__ PO,   // bf16x2 partial O
                                               float2* __restrict__ PM)         // (m, l)
{
    __shared__ float Kt[KV_TILE][68];
    __shared__ float Vt[KV_TILE][68];
    int lane = threadIdx.x;
    int half = lane & 1;            // which 32 dims of the head this lane owns
    int qi   = lane >> 1;           // query within the 32-query group
    int qg = blockIdx.x;            // 0..127 query group
    int h  = blockIdx.y;            // head
    int g  = blockIdx.z >> 1;       // graph
    int c  = blockIdx.z & 1;        // kv chunk
    size_t gbase = (size_t)g * NN;
    int qrow = qg * 32 + qi;

    // load q (32 dims, pre-scaled by 1/sqrt(64))
    const float* qp = &qkv[(gbase + qrow) * 1536 + h * 64 + half * 32];
    float q[32], o[32];
#pragma unroll
    for (int i = 0; i < 32; i += 4) {
        float4 v = *(const float4*)&qp[i];
        q[i] = v.x * 0.125f; q[i + 1] = v.y * 0.125f; q[i + 2] = v.z * 0.125f; q[i + 3] = v.w * 0.125f;
    }
#pragma unroll
    for (int i = 0; i < 32; ++i) o[i] = 0.0f;
    float m = -1e30f, l = 0.0f;

    int sr = lane >> 2;             // staging row 0..15
    int sc = (lane & 3) * 16;       // staging col
    for (int t0 = c * CHUNK_KEYS; t0 < (c + 1) * CHUNK_KEYS; t0 += KV_TILE) {
        const float* kp = &qkv[(gbase + t0 + sr) * 1536 + 512 + h * 64 + sc];
        const float* vp = kp + 512;
#pragma unroll
        for (int i = 0; i < 16; i += 4) {
            float4 kv = *(const float4*)&kp[i];
            *(float4*)&Kt[sr][sc + i] = kv;
            float4 vv = *(const float4*)&vp[i];
            *(float4*)&Vt[sr][sc + i] = vv;
        }
        __syncthreads();
#pragma unroll 1
        for (int j = 0; j < KV_TILE; ++j) {
            const float* kr = &Kt[j][half * 32];
            float s = 0.0f;
#pragma unroll
            for (int i = 0; i < 32; i += 4) {
                float4 kv = *(const float4*)&kr[i];
                s = fmaf(q[i], kv.x, s);
                s = fmaf(q[i + 1], kv.y, s);
                s = fmaf(q[i + 2], kv.z, s);
                s = fmaf(q[i + 3], kv.w, s);
            }
            s += __shfl_xor(s, 1);
            if (s > m) {
                float corr = __expf(m - s);
                l *= corr;
#pragma unroll
                for (int i = 0; i < 32; ++i) o[i] *= corr;
                m = s;
            }
            float p = __expf(s - m);
            l += p;
            const float* vr = &Vt[j][half * 32];
#pragma unroll
            for (int i = 0; i < 32; i += 4) {
                float4 vv = *(const float4*)&vr[i];
                o[i]     = fmaf(p, vv.x, o[i]);
                o[i + 1] = fmaf(p, vv.y, o[i + 1]);
                o[i + 2] = fmaf(p, vv.z, o[i + 2]);
                o[i + 3] = fmaf(p, vv.w, o[i + 3]);
            }
        }
        __syncthreads();
    }

    // write partials: slot = ((g*8+h)*NCHUNK + c)*NN + qrow
    size_t slot = (((size_t)g * 8 + h) * NCHUNK + c) * NN + qrow;
    if (half == 0) PM[slot] = make_float2(m, l);
    unsigned int* pw = &PO[slot * 32 + half * 16];   // 32 uints = 64 bf16 per slot
#pragma unroll
    for (int i = 0; i < 32; i += 2)
        pw[i >> 1] = pack_bf16_2(o[i], o[i + 1]);
}

// combine partials -> ctx
__global__ __launch_bounds__(256) void k_combine(const unsigned int* __restrict__ PO,
                                                 const float2* __restrict__ PM,
                                                 float* __restrict__ ctx)
{
    // one thread per 8 dims: idx over g(2) * h(8) * q(4096) * d8(8)
    int idx = blockIdx.x * 256 + threadIdx.x;
    int d8 = idx & 7;
    int q  = (idx >> 3) & (NN - 1);
    int h  = (idx >> 15) & 7;
    int g  = idx >> 18;
    size_t slot0 = (((size_t)g * 8 + h) * NCHUNK + 0) * NN + q;
    size_t slot1 = slot0 + NN;
    float2 ml0 = PM[slot0], ml1 = PM[slot1];
    float M = fmaxf(ml0.x, ml1.x);
    float e0 = __expf(ml0.x - M), e1 = __expf(ml1.x - M);
    float inv = 1.0f / (ml0.y * e0 + ml1.y * e1);
    e0 *= inv; e1 *= inv;
    uint4 a = *(const uint4*)&PO[slot0 * 32 + d8 * 4];
    uint4 b = *(const uint4*)&PO[slot1 * 32 + d8 * 4];
    float* op = &ctx[((size_t)g * NN + q) * NHID + h * 64 + d8 * 8];
    float4 r0, r1;
    r0.x = bf16_lo(a.x) * e0 + bf16_lo(b.x) * e1;
    r0.y = bf16_hi(a.x) * e0 + bf16_hi(b.x) * e1;
    r0.z = bf16_lo(a.y) * e0 + bf16_lo(b.y) * e1;
    r0.w = bf16_hi(a.y) * e0 + bf16_hi(b.y) * e1;
    r1.x = bf16_lo(a.z) * e0 + bf16_lo(b.z) * e1;
    r1.y = bf16_hi(a.z) * e0 + bf16_hi(b.z) * e1;
    r1.z = bf16_lo(a.w) * e0 + bf16_lo(b.w) * e1;
    r1.w = bf16_hi(a.w) * e0 + bf16_hi(b.w) * e1;
    *(float4*)&op[0] = r0;
    *(float4*)&op[4] = r1;
}

// ---------------- fused residual-add + LayerNorm (512 cols, in place on x) ----------------
__global__ __launch_bounds__(256) void k_add_ln(float* __restrict__ x, const float* __restrict__ y,
                                                const float* __restrict__ g, const float* __restrict__ bb)
{
    int r = blockIdx.x, tid = threadIdx.x;
    int c = tid * 2;
    float2 xv = *(float2*)&x[(size_t)r * NHID + c];
    float2 yv = *(const float2*)&y[(size_t)r * NHID + c];
    float a0 = xv.x + yv.x, a1 = xv.y + yv.y;
    float s = a0 + a1;
    float qs = a0 * a0 + a1 * a1;
#pragma unroll
    for (int off = 32; off > 0; off >>= 1) {
        s  += __shfl_xor(s, off);
        qs += __shfl_xor(qs, off);
    }
    __shared__ float ss[4], qq[4];
    int w = tid >> 6;
    if ((tid & 63) == 0) { ss[w] = s; qq[w] = qs; }
    __syncthreads();
    s  = ss[0] + ss[1] + ss[2] + ss[3];
    qs = qq[0] + qq[1] + qq[2] + qq[3];
    float mu  = s * (1.0f / NHID);
    float var = qs * (1.0f / NHID) - mu * mu;
    float rs = rsqrtf(var + 1e-5f);
    float2 gv = *(const float2*)&g[c];
    float2 bv = *(const float2*)&bb[c];
    float o0 = (a0 - mu) * rs * gv.x + bv.x;
    float o1 = (a1 - mu) * rs * gv.y + bv.y;
    *(float2*)&x[(size_t)r * NHID + c] = make_float2(o0, o1);
}

// ---------------- per-segment mean (segments are contiguous 256-row blocks) ----------------
__global__ __launch_bounds__(512) void k_seg_mean(const float* __restrict__ h, float* __restrict__ means)
{
    int b = blockIdx.x;     // 0..15
    int st = blockIdx.y;    // 0..1
    int col = threadIdx.x;  // 0..511
    const float* hp = &h[((size_t)st * NN + (size_t)b * 256) * NHID + col];
    float acc = 0.0f;
    for (int i = 0; i < 256; ++i) acc += hp[(size_t)i * NHID];
    means[((size_t)st * 16 + b) * NHID + col] = acc * (1.0f / 256.0f);
}

// ---------------- MLP head + softmax (single block) ----------------
__global__ __launch_bounds__(512) void k_head(const float* __restrict__ means,
                                              const float* __restrict__ l1w, const float* __restrict__ l1b,
                                              const float* __restrict__ l2w, const float* __restrict__ l2b,
                                              const float* __restrict__ l3w, const float* __restrict__ l3b,
                                              float* __restrict__ out)
{
    __shared__ float hg[16][512];
    __shared__ float t2[16][128];
    int tid = threadIdx.x;
#pragma unroll
    for (int sgm = 0; sgm < 16; ++sgm)
        hg[sgm][tid] = means[sgm * 512 + tid] * means[(16 + sgm) * 512 + tid];
    __syncthreads();
    float rbuf[16];
#pragma unroll
    for (int sgm = 0; sgm < 16; ++sgm) {
        float acc = l1b[tid];
        for (int k = 0; k < 512; ++k) acc = fmaf(hg[sgm][k], l1w[(size_t)tid * 512 + k], acc);
        rbuf[sgm] = acc;
    }
    __syncthreads();
#pragma unroll
    for (int sgm = 0; sgm < 16; ++sgm) hg[sgm][tid] = rbuf[sgm];
    __syncthreads();
    for (int i = tid; i < 16 * 128; i += 512) {
        int bb = i >> 7, n = i & 127;
        float acc = l2b[n];
        for (int k = 0; k < 512; ++k) acc = fmaf(hg[bb][k], l2w[(size_t)n * 512 + k], acc);
        t2[bb][n] = acc;
    }
    __syncthreads();
    if (tid < 16) {
        float v0 = l3b[0], v1 = l3b[1];
        for (int k = 0; k < 128; ++k) {
            float t = t2[tid][k];
            v0 = fmaf(t, l3w[k], v0);
            v1 = fmaf(t, l3w[128 + k], v1);
        }
        float mx = fmaxf(v0, v1);
        float e0 = __expf(v0 - mx), e1 = __expf(v1 - mx);
        float inv = 1.0f / (e0 + e1);
        out[tid * 2 + 0] = e0 * inv;
        out[tid * 2 + 1] = e1 * inv;
    }
}

// ---------------- launch ----------------
extern "C" void kernel_launch(void* const* d_in, const int* in_sizes, int n_in,
                              void* d_out, int out_size, void* d_ws, size_t ws_size,
                              hipStream_t stream)
{
    const float* fea1 = (const float*)d_in[0];
    const float* fea2 = (const float*)d_in[1];
    const int* src1 = (const int*)d_in[2];
    const int* dst1 = (const int*)d_in[3];
    const int* src2 = (const int*)d_in[4];
    const int* dst2 = (const int*)d_in[5];
    const float* W1 = (const float*)d_in[9];
    const float* b1 = (const float*)d_in[10];
    const float* W2 = (const float*)d_in[11];
    const float* b2 = (const float*)d_in[12];
    const float* in_proj_w = (const float*)d_in[13];
    const float* in_proj_b = (const float*)d_in[14];
    const float* out_proj_w = (const float*)d_in[15];
    const float* out_proj_b = (const float*)d_in[16];
    const float* ln1_g = (const float*)d_in[17];
    const float* ln1_b = (const float*)d_in[18];
    const float* ln2_g = (const float*)d_in[19];
    const float* ln2_b = (const float*)d_in[20];
    const float* ff1_w = (const float*)d_in[21];
    const float* ff1_b = (const float*)d_in[22];
    const float* ff2_w = (const float*)d_in[23];
    const float* ff2_b = (const float*)d_in[24];
    const float* l1_w = (const float*)d_in[25];
    const float* l1_b = (const float*)d_in[26];
    const float* l2_w = (const float*)d_in[27];
    const float* l2_b = (const float*)d_in[28];
    const float* l3_w = (const float*)d_in[29];
    const float* l3_b = (const float*)d_in[30];

    float* ws = (float*)d_ws;
    float* SC = ws + OFF_SCALED;
    float* HP = ws + OFF_HPRE;
    float* X  = ws + OFF_X;
    float* QK = ws + OFF_QKV;
    float* CT = ws + OFF_CTX;
    float* ME = ws + OFF_MEANS;
    float* DG = ws + OFF_DEG;
    float* dout1 = DG;
    float* din1  = DG + NN;
    float* dout2 = DG + 2 * NN;
    float* din2  = DG + 3 * NN;

    // zero degree counters and GC1 agg target (ws is poisoned each call)
    hipMemsetAsync(DG, 0, 4 * NN * sizeof(float), stream);
    hipMemsetAsync(X, 0, (size_t)NS * NHID * sizeof(float), stream);

    // degrees
    k_deg_count<<<EE / 256, 256, 0, stream>>>(src1, dst1, src2, dst2, DG);
    k_deg_fin<<<(4 * NN) / 256, 256, 0, stream>>>(DG);

    // GC1: scale -> gemm W1 -> scatter -> finalize(relu)
    {
        long long tq = (long long)NS * (NFEAT / 4);
        k_scale_rows<<<(int)((tq + 255) / 256), 256, 0, stream>>>(fea1, fea2, dout1, dout2, SC, NFEAT);
    }
    k_gemm<<<dim3(NHID / BN, NS / BM), 256, 0, stream>>>(SC, W1, nullptr, HP, NS, NHID, NFEAT, 0);
    k_scatter<<<2 * EE, 256, 0, stream>>>(HP, X, src1, dst1, src2, dst2);
    k_gcfin<<<(NS * 128) / 256, 256, 0, stream>>>(X, din1, din2, b1);

    // encoder: qkv -> attention (split-KV) -> out_proj -> LN1 -> FF -> LN2
    k_gemm<<<dim3(1536 / BN, NS / BM), 256, 0, stream>>>(X, in_proj_w, in_proj_b, QK, NS, 1536, NHID, 0);
    {
        unsigned int* PO = (unsigned int*)SC;   // 2*8*2*4096 slots * 32 uints = 16.78M uints (fits 40MB region)
        float2* PM = (float2*)HP;               // 2*8*2*4096 float2 = 1MB
        k_flash2<<<dim3(NN / 32, 8, 2 * NCHUNK), 64, 0, stream>>>(QK, PO, PM);
        k_combine<<<(2 * 8 * NN * 8) / 256, 256, 0, stream>>>(PO, PM, CT);
    }
    k_gemm<<<dim3(NHID / BN, NS / BM), 256, 0, stream>>>(CT, out_proj_w, out_proj_b, HP, NS, NHID, NHID, 0);
    k_add_ln<<<NS, 256, 0, stream>>>(X, HP, ln1_g, ln1_b);
    k_gemm<<<dim3(DFF / BN, NS / BM), 256, 0, stream>>>(X, ff1_w, ff1_b, QK, NS, DFF, NHID, 1);
    k_gemm<<<dim3(NHID / BN, NS / BM), 256, 0, stream>>>(QK, ff2_w, ff2_b, HP, NS, NHID, DFF, 0);
    k_add_ln<<<NS, 256, 0, stream>>>(X, HP, ln2_g, ln2_b);

    // GC2
    {
        long long tq = (long long)NS * (NHID / 4);
        k_scale_rows<<<(int)((tq + 255) / 256), 256, 0, stream>>>(X, X + (size_t)NN * NHID, dout1, dout2, SC, NHID);
    }
    k_gemm<<<dim3(NHID / BN, NS / BM), 256, 0, stream>>>(SC, W2, nullptr, HP, NS, NHID, NHID, 0);
    hipMemsetAsync(CT, 0, (size_t)NS * NHID * sizeof(float), stream);
    k_scatter<<<2 * EE, 256, 0, stream>>>(HP, CT, src1, dst1, src2, dst2);
    k_gcfin<<<(NS * 128) / 256, 256, 0, stream>>>(CT, din1, din2, b2);

    // readout
    k_seg_mean<<<dim3(16, 2), 512, 0, stream>>>(CT, ME);
    k_head<<<1, 512, 0, stream>>>(ME, l1_w, l1_b, l2_w, l2_b, l3_w, l3_b, (float*)d_out);
}

// Round 3
// 1762.813 us; speedup vs baseline: 2.7165x; 2.4431x over previous
//
#include <hip/hip_runtime.h>
#include <math.h>

#define NN 4096
#define EE 65536
#define NS 8192
#define NFEAT 1280
#define NHID 512
#define DFF 2048

typedef unsigned short u16;
typedef unsigned int u32;
typedef __attribute__((ext_vector_type(8))) short bf16x8;
typedef __attribute__((ext_vector_type(4))) float f32x4;
#define MFMA16(A,B,C) __builtin_amdgcn_mfma_f32_16x16x32_bf16(A,B,C,0,0,0)

// ---------------- workspace offsets (in floats) ----------------
static const size_t OFF_A   = 0ull;          // 8,388,608  : SCb (bf16 8192x1280) / FFb (bf16 8192x2048) / SC2b
static const size_t OFF_HP  = 8388608ull;    // 4,194,304  : fp32 gemm outputs
static const size_t OFF_X   = 12582912ull;   // 4,194,304  : fp32 encoder state
static const size_t OFF_XB  = 16777216ull;   // 2,097,152  : bf16 copy of X
static const size_t OFF_E   = 18874368ull;   // 6,291,456  : QKVb bf16 8192x1536, later AG2 fp32 8192x512
static const size_t OFF_VT  = 25165824ull;   // 2,097,152  : Vtb bf16 [16][64][4096]
static const size_t OFF_CTB = 27262976ull;   // 2,097,152  : CTb bf16 8192x512
static const size_t OFF_W1B = 29360128ull;   // 327,680
static const size_t OFF_IPB = 29687808ull;   // 393,216
static const size_t OFF_OPB = 30081024ull;   // 131,072
static const size_t OFF_F1B = 30212096ull;   // 524,288
static const size_t OFF_F2B = 30736384ull;   // 524,288
static const size_t OFF_W2B = 31260672ull;   // 131,072
static const size_t OFF_ME  = 31391744ull;   // 16,384
static const size_t OFF_DG  = 31408128ull;   // 16,384
// total 31,424,512 floats = 125.7 MiB

__device__ __forceinline__ u16 f2b(float x) {
    u32 u = __float_as_uint(x);
    return (u16)((u + 0x7fffu + ((u >> 16) & 1u)) >> 16);
}

// ---------------- degree kernels ----------------
__global__ __launch_bounds__(256) void k_deg_count(const int* __restrict__ s1, const int* __restrict__ d1,
                                                   const int* __restrict__ s2, const int* __restrict__ d2,
                                                   float* __restrict__ deg)
{
    int e = blockIdx.x * 256 + threadIdx.x;
    if (e < EE) {
        atomicAdd(&deg[s1[e]], 1.0f);
        atomicAdd(&deg[NN + d1[e]], 1.0f);
        atomicAdd(&deg[2 * NN + s2[e]], 1.0f);
        atomicAdd(&deg[3 * NN + d2[e]], 1.0f);
    }
}

__global__ __launch_bounds__(256) void k_deg_fin(float* __restrict__ deg)
{
    int i = blockIdx.x * 256 + threadIdx.x;
    if (i < 4 * NN) deg[i] = rsqrtf(fmaxf(deg[i], 1.0f));
}

// ---------------- fp32 -> bf16 convert (n multiple of 8) ----------------
__global__ __launch_bounds__(256) void k_cvt(const float* __restrict__ src, u16* __restrict__ dst, int n)
{
    int i = (blockIdx.x * 256 + threadIdx.x) * 8;
    if (i >= n) return;
    float4 a = *(const float4*)&src[i];
    float4 b = *(const float4*)&src[i + 4];
    uint4 o;
    o.x = (u32)f2b(a.x) | ((u32)f2b(a.y) << 16);
    o.y = (u32)f2b(a.z) | ((u32)f2b(a.w) << 16);
    o.z = (u32)f2b(b.x) | ((u32)f2b(b.y) << 16);
    o.w = (u32)f2b(b.z) | ((u32)f2b(b.w) << 16);
    *(uint4*)&dst[i] = o;
}

// ---------------- row scale -> bf16 out (stacked 2-graph) ----------------
__global__ __launch_bounds__(256) void k_scale_bf(const float* __restrict__ in1, const float* __restrict__ in2,
                                                  const float* __restrict__ sc1, const float* __restrict__ sc2,
                                                  u16* __restrict__ out, int ncol)
{
    int quads = ncol >> 2;
    long long idx = (long long)blockIdx.x * 256 + threadIdx.x;
    if (idx >= (long long)NS * quads) return;
    int r  = (int)(idx / quads);
    int cq = (int)(idx % quads) * 4;
    const float* in; const float* sc; int rr;
    if (r < NN) { in = in1; sc = sc1; rr = r; } else { in = in2; sc = sc2; rr = r - NN; }
    float4 v = *(const float4*)&in[(size_t)rr * ncol + cq];
    float s = sc[rr];
    uint2 o;
    o.x = (u32)f2b(v.x * s) | ((u32)f2b(v.y * s) << 16);
    o.y = (u32)f2b(v.z * s) | ((u32)f2b(v.w * s) << 16);
    *(uint2*)&out[(size_t)r * ncol + cq] = o;
}

// ---------------- bf16 MFMA GEMM: C[M,N] = A[M,K] @ W[N,K]^T (+bias)(+relu) ----------------
// 128x128 tile, BK=32, 256 threads = 4 waves (2x2), reg-staged LDS.
__global__ __launch_bounds__(256) void k_gemm_bf(const u16* __restrict__ A, const u16* __restrict__ W,
                                                 const float* __restrict__ bias, float* __restrict__ Cf,
                                                 u16* __restrict__ Cb, int M, int N, int K, int relu)
{
    __shared__ u16 As[128 * 32];
    __shared__ u16 Bs[128 * 32];
    int t = threadIdx.x;
    int w = t >> 6, L = t & 63;
    int lm = L & 15, lq = L >> 4;
    int wr = w >> 1, wc = w & 1;
    int row0 = blockIdx.y * 128, col0 = blockIdx.x * 128;
    f32x4 acc[4][4];
#pragma unroll
    for (int i = 0; i < 4; ++i)
#pragma unroll
        for (int j = 0; j < 4; ++j) acc[i][j] = (f32x4){0.f, 0.f, 0.f, 0.f};

    int sr = t >> 2;          // 0..63
    int sk = (t & 3) * 8;     // k element offset
    const u16* Ag = &A[(size_t)row0 * K + sk];
    const u16* Wg = &W[(size_t)col0 * K + sk];

    for (int k0 = 0; k0 < K; k0 += 32) {
        uint4 a0 = *(const uint4*)&Ag[(size_t)sr * K + k0];
        uint4 a1 = *(const uint4*)&Ag[(size_t)(sr + 64) * K + k0];
        uint4 b0 = *(const uint4*)&Wg[(size_t)sr * K + k0];
        uint4 b1 = *(const uint4*)&Wg[(size_t)(sr + 64) * K + k0];
        __syncthreads();
        *(uint4*)&As[sr * 32 + sk] = a0;
        *(uint4*)&As[(sr + 64) * 32 + sk] = a1;
        *(uint4*)&Bs[sr * 32 + sk] = b0;
        *(uint4*)&Bs[(sr + 64) * 32 + sk] = b1;
        __syncthreads();
        bf16x8 af[4], bw[4];
#pragma unroll
        for (int i = 0; i < 4; ++i) {
            af[i] = *(const bf16x8*)&As[(wr * 64 + i * 16 + lm) * 32 + lq * 8];
            bw[i] = *(const bf16x8*)&Bs[(wc * 64 + i * 16 + lm) * 32 + lq * 8];
        }
#pragma unroll
        for (int i = 0; i < 4; ++i)
#pragma unroll
            for (int j = 0; j < 4; ++j)
                acc[i][j] = MFMA16(af[i], bw[j], acc[i][j]);
    }

#pragma unroll
    for (int i = 0; i < 4; ++i) {
        int row = row0 + wr * 64 + i * 16 + lq * 4;
#pragma unroll
        for (int j = 0; j < 4; ++j) {
            int col = col0 + wc * 64 + j * 16 + lm;
            float bv = bias ? bias[col] : 0.0f;
#pragma unroll
            for (int r = 0; r < 4; ++r) {
                float v = acc[i][j][r] + bv;
                if (relu) v = fmaxf(v, 0.0f);
                size_t off = (size_t)(row + r) * N + col;
                if (Cb) Cb[off] = f2b(v);
                else    Cf[off] = v;
            }
        }
    }
}

// ---------------- edge scatter-add ----------------
__global__ __launch_bounds__(256) void k_scatter(const float* __restrict__ h, float* __restrict__ agg,
                                                 const int* __restrict__ s1, const int* __restrict__ d1,
                                                 const int* __restrict__ s2, const int* __restrict__ d2)
{
    int e = blockIdx.x;
    int c = threadIdx.x;
    int s, d, off;
    if (e < EE) { s = s1[e]; d = d1[e]; off = 0; }
    else        { s = s2[e - EE]; d = d2[e - EE]; off = NN; }
    const float* hp = &h[(size_t)(off + s) * NHID];
    float* ap = &agg[(size_t)(off + d) * NHID];
    atomicAdd(&ap[c], hp[c]);
    atomicAdd(&ap[c + 256], hp[c + 256]);
}

// ---------------- GC finalize: x = relu(agg * dinv[r] + b[c]) + bf16 copy ----------------
__global__ __launch_bounds__(256) void k_gcfin(float* __restrict__ agg, const float* __restrict__ sc1,
                                               const float* __restrict__ sc2, const float* __restrict__ bias,
                                               u16* __restrict__ xb)
{
    size_t idx = (size_t)blockIdx.x * 256 + threadIdx.x;
    int r  = (int)(idx >> 7);
    int cq = (int)(idx & 127) * 4;
    float s = (r < NN) ? sc1[r] : sc2[r - NN];
    float4 v = *(float4*)&agg[(size_t)r * NHID + cq];
    float4 b = *(const float4*)&bias[cq];
    v.x = fmaxf(fmaf(v.x, s, b.x), 0.f);
    v.y = fmaxf(fmaf(v.y, s, b.y), 0.f);
    v.z = fmaxf(fmaf(v.z, s, b.z), 0.f);
    v.w = fmaxf(fmaf(v.w, s, b.w), 0.f);
    *(float4*)&agg[(size_t)r * NHID + cq] = v;
    uint2 o;
    o.x = (u32)f2b(v.x) | ((u32)f2b(v.y) << 16);
    o.y = (u32)f2b(v.z) | ((u32)f2b(v.w) << 16);
    *(uint2*)&xb[(size_t)r * NHID + cq] = o;
}

// ---------------- V transpose: QKVb v-part -> Vtb[(g*8+h)*64 + d][k] ----------------
__global__ __launch_bounds__(256) void k_vtrans(const u16* __restrict__ qkvb, u16* __restrict__ vtb)
{
    __shared__ u16 tile[64][65];
    int t = threadIdx.x;
    int kt = blockIdx.x, h = blockIdx.y, g = blockIdx.z;
    int k0 = kt * 64;
    size_t gbase = (size_t)g * NN;
#pragma unroll
    for (int p = 0; p < 4; ++p) {
        int kl = p * 16 + (t >> 4);
        int d  = (t & 15) * 4;
        uint2 v = *(const uint2*)&qkvb[(gbase + k0 + kl) * 1536 + 1024 + h * 64 + d];
        tile[kl][d + 0] = (u16)(v.x & 0xffff);
        tile[kl][d + 1] = (u16)(v.x >> 16);
        tile[kl][d + 2] = (u16)(v.y & 0xffff);
        tile[kl][d + 3] = (u16)(v.y >> 16);
    }
    __syncthreads();
#pragma unroll
    for (int p = 0; p < 4; ++p) {
        int dl = p * 16 + (t >> 4);
        int k4 = (t & 15) * 4;
        u16 v0 = tile[k4 + 0][dl];
        u16 v1 = tile[k4 + 1][dl];
        u16 v2 = tile[k4 + 2][dl];
        u16 v3 = tile[k4 + 3][dl];
        uint2 o;
        o.x = (u32)v0 | ((u32)v1 << 16);
        o.y = (u32)v2 | ((u32)v3 << 16);
        *(uint2*)&vtb[((size_t)(g * 8 + h) * 64 + dl) * (size_t)NN + k0 + k4] = o;
    }
}

// ---------------- MFMA flash attention ----------------
// 1 wave/block, 32 q-rows (2 x 16-row fragment groups), 32-key tiles.
// Q frags direct from global; K bf16 LDS [32][64]; V^T bf16 LDS [64][32]; P via LDS [32][40].
__global__ __launch_bounds__(64) void k_attn(const u16* __restrict__ qkv,   // bf16 [NS][1536]
                                             const u16* __restrict__ vt,    // bf16 [16][64][4096]
                                             u16* __restrict__ ctb)         // bf16 [NS][512]
{
    __shared__ u16 Kt[32 * 64];
    __shared__ u16 Vl[64 * 32];
    __shared__ u16 Pl[32 * 40];
    int L = threadIdx.x;
    int lm = L & 15, lq = L >> 4;
    int qt = blockIdx.x, h = blockIdx.y, g = blockIdx.z;
    size_t gbase = (size_t)g * NN;
    int q0 = qt * 32;

    bf16x8 qa[2][2];
#pragma unroll
    for (int qg = 0; qg < 2; ++qg) {
        const u16* qp = &qkv[(gbase + q0 + qg * 16 + lm) * 1536 + h * 64 + lq * 8];
        qa[qg][0] = *(const bf16x8*)qp;
        qa[qg][1] = *(const bf16x8*)(qp + 32);
    }
    f32x4 ctx[2][4];
#pragma unroll
    for (int qg = 0; qg < 2; ++qg)
#pragma unroll
        for (int n = 0; n < 4; ++n) ctx[qg][n] = (f32x4){0.f, 0.f, 0.f, 0.f};
    float m[2][4], l[2][4];
#pragma unroll
    for (int qg = 0; qg < 2; ++qg)
#pragma unroll
        for (int r = 0; r < 4; ++r) { m[qg][r] = -1e30f; l[qg][r] = 0.0f; }

    const u16* kgb = &qkv[gbase * 1536 + 512 + h * 64];
    const u16* vgb = &vt[(size_t)(g * 8 + h) * 64 * (size_t)NN];

    for (int t0 = 0; t0 < NN; t0 += 32) {
        // stage K tile (32 rows x 64 d) and V^T tile (64 d x 32 k), reg-staged
        const u16* kg = kgb + (size_t)t0 * 1536;
        const u16* vg = vgb + t0;
        uint4 kr[4], vr[4];
#pragma unroll
        for (int c = 0; c < 4; ++c) {
            kr[c] = *(const uint4*)&kg[(size_t)(c * 8 + (L >> 3)) * 1536 + (L & 7) * 8];
            vr[c] = *(const uint4*)&vg[(size_t)(c * 16 + (L >> 2)) * NN + (L & 3) * 8];
        }
#pragma unroll
        for (int c = 0; c < 4; ++c) {
            *(uint4*)&Kt[(c * 8 + (L >> 3)) * 64 + (L & 7) * 8] = kr[c];
            *(uint4*)&Vl[(c * 16 + (L >> 2)) * 32 + (L & 3) * 8] = vr[c];
        }
        // QK^T (compiler orders LDS via lgkmcnt within the single wave)
        f32x4 s[2][2];
#pragma unroll
        for (int kc = 0; kc < 2; ++kc) {
            bf16x8 kb0 = *(const bf16x8*)&Kt[(kc * 16 + lm) * 64 + lq * 8];
            bf16x8 kb1 = *(const bf16x8*)&Kt[(kc * 16 + lm) * 64 + 32 + lq * 8];
#pragma unroll
            for (int qg = 0; qg < 2; ++qg) {
                f32x4 z = (f32x4){0.f, 0.f, 0.f, 0.f};
                z = MFMA16(qa[qg][0], kb0, z);
                z = MFMA16(qa[qg][1], kb1, z);
                s[qg][kc] = z * 0.125f;
            }
        }
        // online softmax on C-layout (row = lq*4+r, col = kc*16+lm)
#pragma unroll
        for (int qg = 0; qg < 2; ++qg) {
#pragma unroll
            for (int r = 0; r < 4; ++r) {
                float mr = fmaxf(s[qg][0][r], s[qg][1][r]);
                mr = fmaxf(mr, __shfl_xor(mr, 1));
                mr = fmaxf(mr, __shfl_xor(mr, 2));
                mr = fmaxf(mr, __shfl_xor(mr, 4));
                mr = fmaxf(mr, __shfl_xor(mr, 8));
                float mn = fmaxf(m[qg][r], mr);
                float corr = __expf(m[qg][r] - mn);
                m[qg][r] = mn;
                float p0 = __expf(s[qg][0][r] - mn);
                float p1 = __expf(s[qg][1][r] - mn);
                float ps = p0 + p1;
                ps += __shfl_xor(ps, 1);
                ps += __shfl_xor(ps, 2);
                ps += __shfl_xor(ps, 4);
                ps += __shfl_xor(ps, 8);
                l[qg][r] = l[qg][r] * corr + ps;
#pragma unroll
                for (int n = 0; n < 4; ++n) ctx[qg][n][r] *= corr;
                int row = qg * 16 + lq * 4 + r;
                Pl[row * 40 + lm] = f2b(p0);
                Pl[row * 40 + 16 + lm] = f2b(p1);
            }
        }
        // PV
        bf16x8 vb[4];
#pragma unroll
        for (int n = 0; n < 4; ++n)
            vb[n] = *(const bf16x8*)&Vl[(n * 16 + lm) * 32 + lq * 8];
#pragma unroll
        for (int qg = 0; qg < 2; ++qg) {
            bf16x8 pa = *(const bf16x8*)&Pl[(qg * 16 + lm) * 40 + lq * 8];
#pragma unroll
            for (int n = 0; n < 4; ++n)
                ctx[qg][n] = MFMA16(pa, vb[n], ctx[qg][n]);
        }
    }

    // epilogue
#pragma unroll
    for (int qg = 0; qg < 2; ++qg) {
        float inv[4];
#pragma unroll
        for (int r = 0; r < 4; ++r) inv[r] = 1.0f / l[qg][r];
#pragma unroll
        for (int n = 0; n < 4; ++n)
#pragma unroll
            for (int r = 0; r < 4; ++r) {
                int row = q0 + qg * 16 + lq * 4 + r;
                int col = h * 64 + n * 16 + lm;
                ctb[(gbase + row) * NHID + col] = f2b(ctx[qg][n][r] * inv[r]);
            }
    }
}

// ---------------- fused residual-add + LayerNorm + bf16 copy ----------------
__global__ __launch_bounds__(256) void k_add_ln(float* __restrict__ x, const float* __restrict__ y,
                                                const float* __restrict__ g, const float* __restrict__ bb,
                                                u16* __restrict__ xb)
{
    int r = blockIdx.x, tid = threadIdx.x;
    int c = tid * 2;
    float2 xv = *(float2*)&x[(size_t)r * NHID + c];
    float2 yv = *(const float2*)&y[(size_t)r * NHID + c];
    float a0 = xv.x + yv.x, a1 = xv.y + yv.y;
    float s = a0 + a1;
    float qs = a0 * a0 + a1 * a1;
#pragma unroll
    for (int off = 32; off > 0; off >>= 1) {
        s  += __shfl_xor(s, off);
        qs += __shfl_xor(qs, off);
    }
    __shared__ float ss[4], qq[4];
    int w = tid >> 6;
    if ((tid & 63) == 0) { ss[w] = s; qq[w] = qs; }
    __syncthreads();
    s  = ss[0] + ss[1] + ss[2] + ss[3];
    qs = qq[0] + qq[1] + qq[2] + qq[3];
    float mu  = s * (1.0f / NHID);
    float var = qs * (1.0f / NHID) - mu * mu;
    float rs = rsqrtf(var + 1e-5f);
    float2 gv = *(const float2*)&g[c];
    float2 bv = *(const float2*)&bb[c];
    float o0 = (a0 - mu) * rs * gv.x + bv.x;
    float o1 = (a1 - mu) * rs * gv.y + bv.y;
    *(float2*)&x[(size_t)r * NHID + c] = make_float2(o0, o1);
    u32 o = (u32)f2b(o0) | ((u32)f2b(o1) << 16);
    *(u32*)&xb[(size_t)r * NHID + c] = o;
}

// ---------------- per-segment mean (contiguous 256-row segments) ----------------
__global__ __launch_bounds__(512) void k_seg_mean(const float* __restrict__ h, float* __restrict__ means)
{
    int b = blockIdx.x;
    int st = blockIdx.y;
    int col = threadIdx.x;
    const float* hp = &h[((size_t)st * NN + (size_t)b * 256) * NHID + col];
    float acc = 0.0f;
    for (int i = 0; i < 256; ++i) acc += hp[(size_t)i * NHID];
    means[((size_t)st * 16 + b) * NHID + col] = acc * (1.0f / 256.0f);
}

// ---------------- MLP head + softmax ----------------
__global__ __launch_bounds__(512) void k_head(const float* __restrict__ means,
                                              const float* __restrict__ l1w, const float* __restrict__ l1b,
                                              const float* __restrict__ l2w, const float* __restrict__ l2b,
                                              const float* __restrict__ l3w, const float* __restrict__ l3b,
                                              float* __restrict__ out)
{
    __shared__ float hg[16][512];
    __shared__ float t2[16][128];
    int tid = threadIdx.x;
#pragma unroll
    for (int sgm = 0; sgm < 16; ++sgm)
        hg[sgm][tid] = means[sgm * 512 + tid] * means[(16 + sgm) * 512 + tid];
    __syncthreads();
    float rbuf[16];
#pragma unroll
    for (int sgm = 0; sgm < 16; ++sgm) {
        float acc = l1b[tid];
        for (int k = 0; k < 512; ++k) acc = fmaf(hg[sgm][k], l1w[(size_t)tid * 512 + k], acc);
        rbuf[sgm] = acc;
    }
    __syncthreads();
#pragma unroll
    for (int sgm = 0; sgm < 16; ++sgm) hg[sgm][tid] = rbuf[sgm];
    __syncthreads();
    for (int i = tid; i < 16 * 128; i += 512) {
        int bb = i >> 7, n = i & 127;
        float acc = l2b[n];
        for (int k = 0; k < 512; ++k) acc = fmaf(hg[bb][k], l2w[(size_t)n * 512 + k], acc);
        t2[bb][n] = acc;
    }
    __syncthreads();
    if (tid < 16) {
        float v0 = l3b[0], v1 = l3b[1];
        for (int k = 0; k < 128; ++k) {
            float t = t2[tid][k];
            v0 = fmaf(t, l3w[k], v0);
            v1 = fmaf(t, l3w[128 + k], v1);
        }
        float mx = fmaxf(v0, v1);
        float e0 = __expf(v0 - mx), e1 = __expf(v1 - mx);
        float inv = 1.0f / (e0 + e1);
        out[tid * 2 + 0] = e0 * inv;
        out[tid * 2 + 1] = e1 * inv;
    }
}

// ---------------- launch ----------------
extern "C" void kernel_launch(void* const* d_in, const int* in_sizes, int n_in,
                              void* d_out, int out_size, void* d_ws, size_t ws_size,
                              hipStream_t stream)
{
    const float* fea1 = (const float*)d_in[0];
    const float* fea2 = (const float*)d_in[1];
    const int* src1 = (const int*)d_in[2];
    const int* dst1 = (const int*)d_in[3];
    const int* src2 = (const int*)d_in[4];
    const int* dst2 = (const int*)d_in[5];
    const float* W1 = (const float*)d_in[9];
    const float* b1 = (const float*)d_in[10];
    const float* W2 = (const float*)d_in[11];
    const float* b2 = (const float*)d_in[12];
    const float* in_proj_w = (const float*)d_in[13];
    const float* in_proj_b = (const float*)d_in[14];
    const float* out_proj_w = (const float*)d_in[15];
    const float* out_proj_b = (const float*)d_in[16];
    const float* ln1_g = (const float*)d_in[17];
    const float* ln1_b = (const float*)d_in[18];
    const float* ln2_g = (const float*)d_in[19];
    const float* ln2_b = (const float*)d_in[20];
    const float* ff1_w = (const float*)d_in[21];
    const float* ff1_b = (const float*)d_in[22];
    const float* ff2_w = (const float*)d_in[23];
    const float* ff2_b = (const float*)d_in[24];
    const float* l1_w = (const float*)d_in[25];
    const float* l1_b = (const float*)d_in[26];
    const float* l2_w = (const float*)d_in[27];
    const float* l2_b = (const float*)d_in[28];
    const float* l3_w = (const float*)d_in[29];
    const float* l3_b = (const float*)d_in[30];

    float* ws = (float*)d_ws;
    u16*  Ab   = (u16*)(ws + OFF_A);     // SCb / FFb / SC2b
    float* HP  = ws + OFF_HP;
    float* X   = ws + OFF_X;
    u16*  Xb   = (u16*)(ws + OFF_XB);
    u16*  QKVb = (u16*)(ws + OFF_E);
    float* AG2 = ws + OFF_E;
    u16*  Vtb  = (u16*)(ws + OFF_VT);
    u16*  CTb  = (u16*)(ws + OFF_CTB);
    u16*  W1b  = (u16*)(ws + OFF_W1B);
    u16*  IPb  = (u16*)(ws + OFF_IPB);
    u16*  OPb  = (u16*)(ws + OFF_OPB);
    u16*  F1b  = (u16*)(ws + OFF_F1B);
    u16*  F2b  = (u16*)(ws + OFF_F2B);
    u16*  W2b  = (u16*)(ws + OFF_W2B);
    float* ME  = ws + OFF_ME;
    float* DG  = ws + OFF_DG;
    float* dout1 = DG;
    float* din1  = DG + NN;
    float* dout2 = DG + 2 * NN;
    float* din2  = DG + 3 * NN;

    hipMemsetAsync(DG, 0, 4 * NN * sizeof(float), stream);
    hipMemsetAsync(X, 0, (size_t)NS * NHID * sizeof(float), stream);

    k_deg_count<<<EE / 256, 256, 0, stream>>>(src1, dst1, src2, dst2, DG);
    k_deg_fin<<<(4 * NN) / 256, 256, 0, stream>>>(DG);

    // weight conversions
    k_cvt<<<(NHID * NFEAT / 8 + 255) / 256, 256, 0, stream>>>(W1, W1b, NHID * NFEAT);
    k_cvt<<<(3 * NHID * NHID / 8 + 255) / 256, 256, 0, stream>>>(in_proj_w, IPb, 3 * NHID * NHID);
    k_cvt<<<(NHID * NHID / 8 + 255) / 256, 256, 0, stream>>>(out_proj_w, OPb, NHID * NHID);
    k_cvt<<<(DFF * NHID / 8 + 255) / 256, 256, 0, stream>>>(ff1_w, F1b, DFF * NHID);
    k_cvt<<<(NHID * DFF / 8 + 255) / 256, 256, 0, stream>>>(ff2_w, F2b, NHID * DFF);
    k_cvt<<<(NHID * NHID / 8 + 255) / 256, 256, 0, stream>>>(W2, W2b, NHID * NHID);

    // GC1
    {
        long long tq = (long long)NS * (NFEAT / 4);
        k_scale_bf<<<(int)((tq + 255) / 256), 256, 0, stream>>>(fea1, fea2, dout1, dout2, Ab, NFEAT);
    }
    k_gemm_bf<<<dim3(NHID / 128, NS / 128), 256, 0, stream>>>(Ab, W1b, nullptr, HP, nullptr, NS, NHID, NFEAT, 0);
    k_scatter<<<2 * EE, 256, 0, stream>>>(HP, X, src1, dst1, src2, dst2);
    k_gcfin<<<(NS * 128) / 256, 256, 0, stream>>>(X, din1, din2, b1, Xb);

    // encoder
    k_gemm_bf<<<dim3(1536 / 128, NS / 128), 256, 0, stream>>>(Xb, IPb, in_proj_b, nullptr, QKVb, NS, 1536, NHID, 0);
    k_vtrans<<<dim3(NN / 64, 8, 2), 256, 0, stream>>>(QKVb, Vtb);
    k_attn<<<dim3(NN / 32, 8, 2), 64, 0, stream>>>(QKVb, Vtb, CTb);
    k_gemm_bf<<<dim3(NHID / 128, NS / 128), 256, 0, stream>>>(CTb, OPb, out_proj_b, HP, nullptr, NS, NHID, NHID, 0);
    k_add_ln<<<NS, 256, 0, stream>>>(X, HP, ln1_g, ln1_b, Xb);
    k_gemm_bf<<<dim3(DFF / 128, NS / 128), 256, 0, stream>>>(Xb, F1b, ff1_b, nullptr, Ab, NS, DFF, NHID, 1);
    k_gemm_bf<<<dim3(NHID / 128, NS / 128), 256, 0, stream>>>(Ab, F2b, ff2_b, HP, nullptr, NS, NHID, DFF, 0);
    k_add_ln<<<NS, 256, 0, stream>>>(X, HP, ln2_g, ln2_b, Xb);

    // GC2
    {
        long long tq = (long long)NS * (NHID / 4);
        k_scale_bf<<<(int)((tq + 255) / 256), 256, 0, stream>>>(X, X + (size_t)NN * NHID, dout1, dout2, Ab, NHID);
    }
    k_gemm_bf<<<dim3(NHID / 128, NS / 128), 256, 0, stream>>>(Ab, W2b, nullptr, HP, nullptr, NS, NHID, NHID, 0);
    hipMemsetAsync(AG2, 0, (size_t)NS * NHID * sizeof(float), stream);
    k_scatter<<<2 * EE, 256, 0, stream>>>(HP, AG2, src1, dst1, src2, dst2);
    k_gcfin<<<(NS * 128) / 256, 256, 0, stream>>>(AG2, din1, din2, b2, Xb);

    // readout
    k_seg_mean<<<dim3(16, 2), 512, 0, stream>>>(AG2, ME);
    k_head<<<1, 512, 0, stream>>>(ME, l1_w, l1_b, l2_w, l2_b, l3_w, l3_b, (float*)d_out);
}

// Round 4
// 879.044 us; speedup vs baseline: 5.4477x; 2.0054x over previous
//
#include <hip/hip_runtime.h>
#include <math.h>

#define NN 4096
#define EE 65536
#define NS 8192
#define NFEAT 1280
#define NHID 512
#define DFF 2048

typedef unsigned short u16;
typedef unsigned int u32;
typedef __attribute__((ext_vector_type(8))) short bf16x8;
typedef __attribute__((ext_vector_type(4))) float f32x4;
#define MFMA16(A,B,C) __builtin_amdgcn_mfma_f32_16x16x32_bf16(A,B,C,0,0,0)

// ---------------- workspace offsets (in floats) ----------------
static const size_t OFF_A   = 0ull;          // 8,388,608  : SCb (bf16 8192x1280) / FFb (bf16 8192x2048) / SC2b
static const size_t OFF_HP  = 8388608ull;    // 4,194,304  : fp32 gemm outputs
static const size_t OFF_X   = 12582912ull;   // 4,194,304  : fp32 encoder state
static const size_t OFF_XB  = 16777216ull;   // 2,097,152  : bf16 copy of X
static const size_t OFF_E   = 18874368ull;   // 6,291,456  : QKVb bf16 8192x1536, later AG2 fp32 8192x512
static const size_t OFF_VT  = 25165824ull;   // 2,097,152  : Vtb bf16 [16][64][4096]
static const size_t OFF_CTB = 27262976ull;   // 2,097,152  : CTb bf16 8192x512
static const size_t OFF_W1B = 29360128ull;   // 327,680
static const size_t OFF_IPB = 29687808ull;   // 393,216
static const size_t OFF_OPB = 30081024ull;   // 131,072
static const size_t OFF_F1B = 30212096ull;   // 524,288
static const size_t OFF_F2B = 30736384ull;   // 524,288
static const size_t OFF_W2B = 31260672ull;   // 131,072
static const size_t OFF_ME  = 31391744ull;   // 16,384
static const size_t OFF_DG  = 31408128ull;   // 16,384
static const size_t OFF_INT = 31424512ull;   // 164,096 ints (CSR)
// total ~31.59M floats = 126.4 MiB

// int-region offsets (in ints, from OFF_INT)
#define IH_S1 0
#define IH_D1 4096
#define IH_S2 8192
#define IH_D2 12288
#define IO_F1 16384
#define IO_F2 20608
#define IC_1  24832
#define IC_2  28928
#define IE_1  33024
#define IE_2  98560

__device__ __forceinline__ u16 f2b(float x) {
    u32 u = __float_as_uint(x);
    return (u16)((u + 0x7fffu + ((u >> 16) & 1u)) >> 16);
}

// ---------------- CSR build ----------------
__global__ __launch_bounds__(256) void k_hist(const int* __restrict__ s1, const int* __restrict__ d1,
                                              const int* __restrict__ s2, const int* __restrict__ d2,
                                              int* __restrict__ I)
{
    int e = blockIdx.x * 256 + threadIdx.x;
    if (e < EE) {
        atomicAdd(&I[IH_S1 + s1[e]], 1);
        atomicAdd(&I[IH_D1 + d1[e]], 1);
        atomicAdd(&I[IH_S2 + s2[e]], 1);
        atomicAdd(&I[IH_D2 + d2[e]], 1);
    }
}

__global__ __launch_bounds__(256) void k_deg_fin(const int* __restrict__ I, float* __restrict__ deg)
{
    int i = blockIdx.x * 256 + threadIdx.x;
    if (i < 4 * NN) deg[i] = rsqrtf(fmaxf((float)I[i], 1.0f));
}

// exclusive scan of the dst histogram -> offsets + cursors (one block per graph)
__global__ __launch_bounds__(256) void k_scan(int* __restrict__ I)
{
    int b = blockIdx.x;
    const int* hist = I + (b ? IH_D2 : IH_D1);
    int* offs = I + (b ? IO_F2 : IO_F1);
    int* cur  = I + (b ? IC_2 : IC_1);
    __shared__ int part[256];
    int t = threadIdx.x;
    int base = t * 16;
    int loc[16];
    int s = 0;
#pragma unroll
    for (int i = 0; i < 16; ++i) { loc[i] = s; s += hist[base + i]; }
    part[t] = s;
    __syncthreads();
    if (t == 0) {
        int a = 0;
        for (int i = 0; i < 256; ++i) { int v = part[i]; part[i] = a; a += v; }
        offs[NN] = a;
    }
    __syncthreads();
    int p = part[t];
#pragma unroll
    for (int i = 0; i < 16; ++i) { offs[base + i] = p + loc[i]; cur[base + i] = p + loc[i]; }
}

__global__ __launch_bounds__(256) void k_fill(const int* __restrict__ s1, const int* __restrict__ d1,
                                              const int* __restrict__ s2, const int* __restrict__ d2,
                                              int* __restrict__ I)
{
    int e = blockIdx.x * 256 + threadIdx.x;
    if (e < EE) {
        int p1 = atomicAdd(&I[IC_1 + d1[e]], 1);
        I[IE_1 + p1] = s1[e];
        int p2 = atomicAdd(&I[IC_2 + d2[e]], 1);
        I[IE_2 + p2] = s2[e];
    }
}

// ---------------- fp32 -> bf16 convert (n multiple of 8) ----------------
__global__ __launch_bounds__(256) void k_cvt(const float* __restrict__ src, u16* __restrict__ dst, int n)
{
    int i = (blockIdx.x * 256 + threadIdx.x) * 8;
    if (i >= n) return;
    float4 a = *(const float4*)&src[i];
    float4 b = *(const float4*)&src[i + 4];
    uint4 o;
    o.x = (u32)f2b(a.x) | ((u32)f2b(a.y) << 16);
    o.y = (u32)f2b(a.z) | ((u32)f2b(a.w) << 16);
    o.z = (u32)f2b(b.x) | ((u32)f2b(b.y) << 16);
    o.w = (u32)f2b(b.z) | ((u32)f2b(b.w) << 16);
    *(uint4*)&dst[i] = o;
}

// ---------------- row scale -> bf16 out (stacked 2-graph) ----------------
__global__ __launch_bounds__(256) void k_scale_bf(const float* __restrict__ in1, const float* __restrict__ in2,
                                                  const float* __restrict__ sc1, const float* __restrict__ sc2,
                                                  u16* __restrict__ out, int ncol)
{
    int quads = ncol >> 2;
    long long idx = (long long)blockIdx.x * 256 + threadIdx.x;
    if (idx >= (long long)NS * quads) return;
    int r  = (int)(idx / quads);
    int cq = (int)(idx % quads) * 4;
    const float* in; const float* sc; int rr;
    if (r < NN) { in = in1; sc = sc1; rr = r; } else { in = in2; sc = sc2; rr = r - NN; }
    float4 v = *(const float4*)&in[(size_t)rr * ncol + cq];
    float s = sc[rr];
    uint2 o;
    o.x = (u32)f2b(v.x * s) | ((u32)f2b(v.y * s) << 16);
    o.y = (u32)f2b(v.z * s) | ((u32)f2b(v.w * s) << 16);
    *(uint2*)&out[(size_t)r * ncol + cq] = o;
}

// ---------------- bf16 MFMA GEMM: C[M,N] = A[M,K] @ W[N,K]^T (+bias)(+relu) ----------------
__global__ __launch_bounds__(256) void k_gemm_bf(const u16* __restrict__ A, const u16* __restrict__ W,
                                                 const float* __restrict__ bias, float* __restrict__ Cf,
                                                 u16* __restrict__ Cb, int M, int N, int K, int relu)
{
    __shared__ u16 As[128 * 32];
    __shared__ u16 Bs[128 * 32];
    int t = threadIdx.x;
    int w = t >> 6, L = t & 63;
    int lm = L & 15, lq = L >> 4;
    int wr = w >> 1, wc = w & 1;
    int row0 = blockIdx.y * 128, col0 = blockIdx.x * 128;
    f32x4 acc[4][4];
#pragma unroll
    for (int i = 0; i < 4; ++i)
#pragma unroll
        for (int j = 0; j < 4; ++j) acc[i][j] = (f32x4){0.f, 0.f, 0.f, 0.f};

    int sr = t >> 2;
    int sk = (t & 3) * 8;
    const u16* Ag = &A[(size_t)row0 * K + sk];
    const u16* Wg = &W[(size_t)col0 * K + sk];

    for (int k0 = 0; k0 < K; k0 += 32) {
        uint4 a0 = *(const uint4*)&Ag[(size_t)sr * K + k0];
        uint4 a1 = *(const uint4*)&Ag[(size_t)(sr + 64) * K + k0];
        uint4 b0 = *(const uint4*)&Wg[(size_t)sr * K + k0];
        uint4 b1 = *(const uint4*)&Wg[(size_t)(sr + 64) * K + k0];
        __syncthreads();
        *(uint4*)&As[sr * 32 + sk] = a0;
        *(uint4*)&As[(sr + 64) * 32 + sk] = a1;
        *(uint4*)&Bs[sr * 32 + sk] = b0;
        *(uint4*)&Bs[(sr + 64) * 32 + sk] = b1;
        __syncthreads();
        bf16x8 af[4], bw[4];
#pragma unroll
        for (int i = 0; i < 4; ++i) {
            af[i] = *(const bf16x8*)&As[(wr * 64 + i * 16 + lm) * 32 + lq * 8];
            bw[i] = *(const bf16x8*)&Bs[(wc * 64 + i * 16 + lm) * 32 + lq * 8];
        }
#pragma unroll
        for (int i = 0; i < 4; ++i)
#pragma unroll
            for (int j = 0; j < 4; ++j)
                acc[i][j] = MFMA16(af[i], bw[j], acc[i][j]);
    }

#pragma unroll
    for (int i = 0; i < 4; ++i) {
        int row = row0 + wr * 64 + i * 16 + lq * 4;
#pragma unroll
        for (int j = 0; j < 4; ++j) {
            int col = col0 + wc * 64 + j * 16 + lm;
            float bv = bias ? bias[col] : 0.0f;
#pragma unroll
            for (int r = 0; r < 4; ++r) {
                float v = acc[i][j][r] + bv;
                if (relu) v = fmaxf(v, 0.0f);
                size_t off = (size_t)(row + r) * N + col;
                if (Cb) Cb[off] = f2b(v);
                else    Cf[off] = v;
            }
        }
    }
}

// ---------------- CSR gather + GC finalize: x[r] = relu(sum_in(hp) * din[r] + b) ----------------
__global__ __launch_bounds__(256) void k_gather(const float* __restrict__ hp, const int* __restrict__ I,
                                                const float* __restrict__ din1, const float* __restrict__ din2,
                                                const float* __restrict__ bias,
                                                float* __restrict__ xout, u16* __restrict__ xb)
{
    int r = blockIdx.x, c = threadIdx.x;
    int g = r >> 12, rl = r & (NN - 1);
    const int* off = I + (g ? IO_F2 : IO_F1);
    const int* eid = I + (g ? IE_2 : IE_1);
    int beg = off[rl], end = off[rl + 1];
    const float* base = hp + ((size_t)g << 12) * NHID;
    float a0 = 0.f, a1 = 0.f;
    for (int i = beg; i < end; ++i) {
        const float* row = base + (size_t)eid[i] * NHID;
        a0 += row[c];
        a1 += row[c + 256];
    }
    float s = (g ? din2 : din1)[rl];
    float v0 = fmaxf(fmaf(a0, s, bias[c]), 0.f);
    float v1 = fmaxf(fmaf(a1, s, bias[c + 256]), 0.f);
    size_t o = (size_t)r * NHID;
    xout[o + c] = v0;
    xout[o + c + 256] = v1;
    if (xb) {
        xb[o + c] = f2b(v0);
        xb[o + c + 256] = f2b(v1);
    }
}

// ---------------- V transpose: QKVb v-part -> Vtb[(g*8+h)*64 + d][k] ----------------
__global__ __launch_bounds__(256) void k_vtrans(const u16* __restrict__ qkvb, u16* __restrict__ vtb)
{
    __shared__ u16 tile[64][65];
    int t = threadIdx.x;
    int kt = blockIdx.x, h = blockIdx.y, g = blockIdx.z;
    int k0 = kt * 64;
    size_t gbase = (size_t)g * NN;
#pragma unroll
    for (int p = 0; p < 4; ++p) {
        int kl = p * 16 + (t >> 4);
        int d  = (t & 15) * 4;
        uint2 v = *(const uint2*)&qkvb[(gbase + k0 + kl) * 1536 + 1024 + h * 64 + d];
        tile[kl][d + 0] = (u16)(v.x & 0xffff);
        tile[kl][d + 1] = (u16)(v.x >> 16);
        tile[kl][d + 2] = (u16)(v.y & 0xffff);
        tile[kl][d + 3] = (u16)(v.y >> 16);
    }
    __syncthreads();
#pragma unroll
    for (int p = 0; p < 4; ++p) {
        int dl = p * 16 + (t >> 4);
        int k4 = (t & 15) * 4;
        u16 v0 = tile[k4 + 0][dl];
        u16 v1 = tile[k4 + 1][dl];
        u16 v2 = tile[k4 + 2][dl];
        u16 v3 = tile[k4 + 3][dl];
        uint2 o;
        o.x = (u32)v0 | ((u32)v1 << 16);
        o.y = (u32)v2 | ((u32)v3 << 16);
        *(uint2*)&vtb[((size_t)(g * 8 + h) * 64 + dl) * (size_t)NN + k0 + k4] = o;
    }
}

// ---------------- MFMA flash attention (1 wave/block, 32 q-rows, 32-key tiles) ----------------
__global__ __launch_bounds__(64) void k_attn(const u16* __restrict__ qkv,
                                             const u16* __restrict__ vt,
                                             u16* __restrict__ ctb)
{
    __shared__ u16 Kt[32 * 64];
    __shared__ u16 Vl[64 * 32];
    __shared__ u16 Pl[32 * 40];
    int L = threadIdx.x;
    int lm = L & 15, lq = L >> 4;
    int qt = blockIdx.x, h = blockIdx.y, g = blockIdx.z;
    size_t gbase = (size_t)g * NN;
    int q0 = qt * 32;

    bf16x8 qa[2][2];
#pragma unroll
    for (int qg = 0; qg < 2; ++qg) {
        const u16* qp = &qkv[(gbase + q0 + qg * 16 + lm) * 1536 + h * 64 + lq * 8];
        qa[qg][0] = *(const bf16x8*)qp;
        qa[qg][1] = *(const bf16x8*)(qp + 32);
    }
    f32x4 ctx[2][4];
#pragma unroll
    for (int qg = 0; qg < 2; ++qg)
#pragma unroll
        for (int n = 0; n < 4; ++n) ctx[qg][n] = (f32x4){0.f, 0.f, 0.f, 0.f};
    float m[2][4], l[2][4];
#pragma unroll
    for (int qg = 0; qg < 2; ++qg)
#pragma unroll
        for (int r = 0; r < 4; ++r) { m[qg][r] = -1e30f; l[qg][r] = 0.0f; }

    const u16* kgb = &qkv[gbase * 1536 + 512 + h * 64];
    const u16* vgb = &vt[(size_t)(g * 8 + h) * 64 * (size_t)NN];

    for (int t0 = 0; t0 < NN; t0 += 32) {
        const u16* kg = kgb + (size_t)t0 * 1536;
        const u16* vg = vgb + t0;
        uint4 kr[4], vr[4];
#pragma unroll
        for (int c = 0; c < 4; ++c) {
            kr[c] = *(const uint4*)&kg[(size_t)(c * 8 + (L >> 3)) * 1536 + (L & 7) * 8];
            vr[c] = *(const uint4*)&vg[(size_t)(c * 16 + (L >> 2)) * NN + (L & 3) * 8];
        }
#pragma unroll
        for (int c = 0; c < 4; ++c) {
            *(uint4*)&Kt[(c * 8 + (L >> 3)) * 64 + (L & 7) * 8] = kr[c];
            *(uint4*)&Vl[(c * 16 + (L >> 2)) * 32 + (L & 3) * 8] = vr[c];
        }
        f32x4 s[2][2];
#pragma unroll
        for (int kc = 0; kc < 2; ++kc) {
            bf16x8 kb0 = *(const bf16x8*)&Kt[(kc * 16 + lm) * 64 + lq * 8];
            bf16x8 kb1 = *(const bf16x8*)&Kt[(kc * 16 + lm) * 64 + 32 + lq * 8];
#pragma unroll
            for (int qg = 0; qg < 2; ++qg) {
                f32x4 z = (f32x4){0.f, 0.f, 0.f, 0.f};
                z = MFMA16(qa[qg][0], kb0, z);
                z = MFMA16(qa[qg][1], kb1, z);
                s[qg][kc] = z * 0.125f;
            }
        }
#pragma unroll
        for (int qg = 0; qg < 2; ++qg) {
#pragma unroll
            for (int r = 0; r < 4; ++r) {
                float mr = fmaxf(s[qg][0][r], s[qg][1][r]);
                mr = fmaxf(mr, __shfl_xor(mr, 1));
                mr = fmaxf(mr, __shfl_xor(mr, 2));
                mr = fmaxf(mr, __shfl_xor(mr, 4));
                mr = fmaxf(mr, __shfl_xor(mr, 8));
                float mn = fmaxf(m[qg][r], mr);
                float corr = __expf(m[qg][r] - mn);
                m[qg][r] = mn;
                float p0 = __expf(s[qg][0][r] - mn);
                float p1 = __expf(s[qg][1][r] - mn);
                float ps = p0 + p1;
                ps += __shfl_xor(ps, 1);
                ps += __shfl_xor(ps, 2);
                ps += __shfl_xor(ps, 4);
                ps += __shfl_xor(ps, 8);
                l[qg][r] = l[qg][r] * corr + ps;
#pragma unroll
                for (int n = 0; n < 4; ++n) ctx[qg][n][r] *= corr;
                int row = qg * 16 + lq * 4 + r;
                Pl[row * 40 + lm] = f2b(p0);
                Pl[row * 40 + 16 + lm] = f2b(p1);
            }
        }
        bf16x8 vb[4];
#pragma unroll
        for (int n = 0; n < 4; ++n)
            vb[n] = *(const bf16x8*)&Vl[(n * 16 + lm) * 32 + lq * 8];
#pragma unroll
        for (int qg = 0; qg < 2; ++qg) {
            bf16x8 pa = *(const bf16x8*)&Pl[(qg * 16 + lm) * 40 + lq * 8];
#pragma unroll
            for (int n = 0; n < 4; ++n)
                ctx[qg][n] = MFMA16(pa, vb[n], ctx[qg][n]);
        }
    }

#pragma unroll
    for (int qg = 0; qg < 2; ++qg) {
        float inv[4];
#pragma unroll
        for (int r = 0; r < 4; ++r) inv[r] = 1.0f / l[qg][r];
#pragma unroll
        for (int n = 0; n < 4; ++n)
#pragma unroll
            for (int r = 0; r < 4; ++r) {
                int row = q0 + qg * 16 + lq * 4 + r;
                int col = h * 64 + n * 16 + lm;
                ctb[(gbase + row) * NHID + col] = f2b(ctx[qg][n][r] * inv[r]);
            }
    }
}

// ---------------- fused residual-add + LayerNorm + bf16 copy ----------------
__global__ __launch_bounds__(256) void k_add_ln(float* __restrict__ x, const float* __restrict__ y,
                                                const float* __restrict__ g, const float* __restrict__ bb,
                                                u16* __restrict__ xb)
{
    int r = blockIdx.x, tid = threadIdx.x;
    int c = tid * 2;
    float2 xv = *(float2*)&x[(size_t)r * NHID + c];
    float2 yv = *(const float2*)&y[(size_t)r * NHID + c];
    float a0 = xv.x + yv.x, a1 = xv.y + yv.y;
    float s = a0 + a1;
    float qs = a0 * a0 + a1 * a1;
#pragma unroll
    for (int off = 32; off > 0; off >>= 1) {
        s  += __shfl_xor(s, off);
        qs += __shfl_xor(qs, off);
    }
    __shared__ float ss[4], qq[4];
    int w = tid >> 6;
    if ((tid & 63) == 0) { ss[w] = s; qq[w] = qs; }
    __syncthreads();
    s  = ss[0] + ss[1] + ss[2] + ss[3];
    qs = qq[0] + qq[1] + qq[2] + qq[3];
    float mu  = s * (1.0f / NHID);
    float var = qs * (1.0f / NHID) - mu * mu;
    float rs = rsqrtf(var + 1e-5f);
    float2 gv = *(const float2*)&g[c];
    float2 bv = *(const float2*)&bb[c];
    float o0 = (a0 - mu) * rs * gv.x + bv.x;
    float o1 = (a1 - mu) * rs * gv.y + bv.y;
    *(float2*)&x[(size_t)r * NHID + c] = make_float2(o0, o1);
    u32 o = (u32)f2b(o0) | ((u32)f2b(o1) << 16);
    *(u32*)&xb[(size_t)r * NHID + c] = o;
}

// ---------------- per-segment mean (contiguous 256-row segments) ----------------
__global__ __launch_bounds__(512) void k_seg_mean(const float* __restrict__ h, float* __restrict__ means)
{
    int b = blockIdx.x;
    int st = blockIdx.y;
    int col = threadIdx.x;
    const float* hp = &h[((size_t)st * NN + (size_t)b * 256) * NHID + col];
    float acc = 0.0f;
    for (int i = 0; i < 256; ++i) acc += hp[(size_t)i * NHID];
    means[((size_t)st * 16 + b) * NHID + col] = acc * (1.0f / 256.0f);
}

// ---------------- MLP head + softmax (16 blocks, one per segment) ----------------
__global__ __launch_bounds__(256) void k_head(const float* __restrict__ means,
                                              const float* __restrict__ l1w, const float* __restrict__ l1b,
                                              const float* __restrict__ l2w, const float* __restrict__ l2b,
                                              const float* __restrict__ l3w, const float* __restrict__ l3b,
                                              float* __restrict__ out)
{
    __shared__ float hg[512];
    __shared__ float t1[512];
    __shared__ float t2[128];
    int b = blockIdx.x;
    int t = threadIdx.x;
    hg[t]       = means[b * 512 + t]       * means[(16 + b) * 512 + t];
    hg[t + 256] = means[b * 512 + t + 256] * means[(16 + b) * 512 + t + 256];
    __syncthreads();
#pragma unroll
    for (int o = t; o < 512; o += 256) {
        const float* wr = &l1w[(size_t)o * 512];
        float acc = l1b[o];
        for (int k = 0; k < 512; k += 4) {
            float4 w = *(const float4*)&wr[k];
            acc = fmaf(hg[k], w.x, acc);
            acc = fmaf(hg[k + 1], w.y, acc);
            acc = fmaf(hg[k + 2], w.z, acc);
            acc = fmaf(hg[k + 3], w.w, acc);
        }
        t1[o] = acc;
    }
    __syncthreads();
    if (t < 128) {
        const float* wr = &l2w[(size_t)t * 512];
        float acc = l2b[t];
        for (int k = 0; k < 512; k += 4) {
            float4 w = *(const float4*)&wr[k];
            acc = fmaf(t1[k], w.x, acc);
            acc = fmaf(t1[k + 1], w.y, acc);
            acc = fmaf(t1[k + 2], w.z, acc);
            acc = fmaf(t1[k + 3], w.w, acc);
        }
        t2[t] = acc;
    }
    __syncthreads();
    if (t < 64) {
        float p0 = t2[t] * l3w[t] + t2[t + 64] * l3w[t + 64];
        float p1 = t2[t] * l3w[128 + t] + t2[t + 64] * l3w[128 + t + 64];
#pragma unroll
        for (int off = 32; off > 0; off >>= 1) {
            p0 += __shfl_xor(p0, off);
            p1 += __shfl_xor(p1, off);
        }
        if (t == 0) {
            float v0 = p0 + l3b[0], v1 = p1 + l3b[1];
            float mx = fmaxf(v0, v1);
            float e0 = __expf(v0 - mx), e1 = __expf(v1 - mx);
            float inv = 1.0f / (e0 + e1);
            out[b * 2 + 0] = e0 * inv;
            out[b * 2 + 1] = e1 * inv;
        }
    }
}

// ---------------- launch ----------------
extern "C" void kernel_launch(void* const* d_in, const int* in_sizes, int n_in,
                              void* d_out, int out_size, void* d_ws, size_t ws_size,
                              hipStream_t stream)
{
    const float* fea1 = (const float*)d_in[0];
    const float* fea2 = (const float*)d_in[1];
    const int* src1 = (const int*)d_in[2];
    const int* dst1 = (const int*)d_in[3];
    const int* src2 = (const int*)d_in[4];
    const int* dst2 = (const int*)d_in[5];
    const float* W1 = (const float*)d_in[9];
    const float* b1 = (const float*)d_in[10];
    const float* W2 = (const float*)d_in[11];
    const float* b2 = (const float*)d_in[12];
    const float* in_proj_w = (const float*)d_in[13];
    const float* in_proj_b = (const float*)d_in[14];
    const float* out_proj_w = (const float*)d_in[15];
    const float* out_proj_b = (const float*)d_in[16];
    const float* ln1_g = (const float*)d_in[17];
    const float* ln1_b = (const float*)d_in[18];
    const float* ln2_g = (const float*)d_in[19];
    const float* ln2_b = (const float*)d_in[20];
    const float* ff1_w = (const float*)d_in[21];
    const float* ff1_b = (const float*)d_in[22];
    const float* ff2_w = (const float*)d_in[23];
    const float* ff2_b = (const float*)d_in[24];
    const float* l1_w = (const float*)d_in[25];
    const float* l1_b = (const float*)d_in[26];
    const float* l2_w = (const float*)d_in[27];
    const float* l2_b = (const float*)d_in[28];
    const float* l3_w = (const float*)d_in[29];
    const float* l3_b = (const float*)d_in[30];

    float* ws = (float*)d_ws;
    u16*  Ab   = (u16*)(ws + OFF_A);
    float* HP  = ws + OFF_HP;
    float* X   = ws + OFF_X;
    u16*  Xb   = (u16*)(ws + OFF_XB);
    u16*  QKVb = (u16*)(ws + OFF_E);
    float* AG2 = ws + OFF_E;
    u16*  Vtb  = (u16*)(ws + OFF_VT);
    u16*  CTb  = (u16*)(ws + OFF_CTB);
    u16*  W1b  = (u16*)(ws + OFF_W1B);
    u16*  IPb  = (u16*)(ws + OFF_IPB);
    u16*  OPb  = (u16*)(ws + OFF_OPB);
    u16*  F1b  = (u16*)(ws + OFF_F1B);
    u16*  F2b  = (u16*)(ws + OFF_F2B);
    u16*  W2b  = (u16*)(ws + OFF_W2B);
    float* ME  = ws + OFF_ME;
    float* DG  = ws + OFF_DG;
    int*   I   = (int*)(ws + OFF_INT);
    float* dout1 = DG;
    float* din1  = DG + NN;
    float* dout2 = DG + 2 * NN;
    float* din2  = DG + 3 * NN;

    // zero the 4 histograms (64 KB); everything else is fully overwritten
    hipMemsetAsync(I, 0, 4 * NN * sizeof(int), stream);

    // CSR build + degrees
    k_hist<<<EE / 256, 256, 0, stream>>>(src1, dst1, src2, dst2, I);
    k_deg_fin<<<(4 * NN) / 256, 256, 0, stream>>>(I, DG);
    k_scan<<<2, 256, 0, stream>>>(I);
    k_fill<<<EE / 256, 256, 0, stream>>>(src1, dst1, src2, dst2, I);

    // weight conversions
    k_cvt<<<(NHID * NFEAT / 8 + 255) / 256, 256, 0, stream>>>(W1, W1b, NHID * NFEAT);
    k_cvt<<<(3 * NHID * NHID / 8 + 255) / 256, 256, 0, stream>>>(in_proj_w, IPb, 3 * NHID * NHID);
    k_cvt<<<(NHID * NHID / 8 + 255) / 256, 256, 0, stream>>>(out_proj_w, OPb, NHID * NHID);
    k_cvt<<<(DFF * NHID / 8 + 255) / 256, 256, 0, stream>>>(ff1_w, F1b, DFF * NHID);
    k_cvt<<<(NHID * DFF / 8 + 255) / 256, 256, 0, stream>>>(ff2_w, F2b, NHID * DFF);
    k_cvt<<<(NHID * NHID / 8 + 255) / 256, 256, 0, stream>>>(W2, W2b, NHID * NHID);

    // GC1
    {
        long long tq = (long long)NS * (NFEAT / 4);
        k_scale_bf<<<(int)((tq + 255) / 256), 256, 0, stream>>>(fea1, fea2, dout1, dout2, Ab, NFEAT);
    }
    k_gemm_bf<<<dim3(NHID / 128, NS / 128), 256, 0, stream>>>(Ab, W1b, nullptr, HP, nullptr, NS, NHID, NFEAT, 0);
    k_gather<<<NS, 256, 0, stream>>>(HP, I, din1, din2, b1, X, Xb);

    // encoder
    k_gemm_bf<<<dim3(1536 / 128, NS / 128), 256, 0, stream>>>(Xb, IPb, in_proj_b, nullptr, QKVb, NS, 1536, NHID, 0);
    k_vtrans<<<dim3(NN / 64, 8, 2), 256, 0, stream>>>(QKVb, Vtb);
    k_attn<<<dim3(NN / 32, 8, 2), 64, 0, stream>>>(QKVb, Vtb, CTb);
    k_gemm_bf<<<dim3(NHID / 128, NS / 128), 256, 0, stream>>>(CTb, OPb, out_proj_b, HP, nullptr, NS, NHID, NHID, 0);
    k_add_ln<<<NS, 256, 0, stream>>>(X, HP, ln1_g, ln1_b, Xb);
    k_gemm_bf<<<dim3(DFF / 128, NS / 128), 256, 0, stream>>>(Xb, F1b, ff1_b, nullptr, Ab, NS, DFF, NHID, 1);
    k_gemm_bf<<<dim3(NHID / 128, NS / 128), 256, 0, stream>>>(Ab, F2b, ff2_b, HP, nullptr, NS, NHID, DFF, 0);
    k_add_ln<<<NS, 256, 0, stream>>>(X, HP, ln2_g, ln2_b, Xb);

    // GC2
    {
        long long tq = (long long)NS * (NHID / 4);
        k_scale_bf<<<(int)((tq + 255) / 256), 256, 0, stream>>>(X, X + (size_t)NN * NHID, dout1, dout2, Ab, NHID);
    }
    k_gemm_bf<<<dim3(NHID / 128, NS / 128), 256, 0, stream>>>(Ab, W2b, nullptr, HP, nullptr, NS, NHID, NHID, 0);
    k_gather<<<NS, 256, 0, stream>>>(HP, I, din1, din2, b2, AG2, nullptr);

    // readout
    k_seg_mean<<<dim3(16, 2), 512, 0, stream>>>(AG2, ME);
    k_head<<<16, 256, 0, stream>>>(ME, l1_w, l1_b, l2_w, l2_b, l3_w, l3_b, (float*)d_out);
}

// Round 5
// 767.643 us; speedup vs baseline: 6.2382x; 1.1451x over previous
//
#include <hip/hip_runtime.h>
#include <math.h>

#define NN 4096
#define EE 65536
#define NS 8192
#define NFEAT 1280
#define NHID 512
#define DFF 2048

typedef unsigned short u16;
typedef unsigned int u32;
typedef __attribute__((ext_vector_type(8))) short bf16x8;
typedef __attribute__((ext_vector_type(4))) float f32x4;
#define MFMA16(A,B,C) __builtin_amdgcn_mfma_f32_16x16x32_bf16(A,B,C,0,0,0)

// ---------------- workspace offsets (in floats) ----------------
static const size_t OFF_A   = 0ull;          // 8,388,608  : SCb (bf16 8192x1280) / FFb (bf16 8192x2048) / SC2b
static const size_t OFF_HP  = 8388608ull;    // 4,194,304  : fp32 gemm outputs
static const size_t OFF_X   = 12582912ull;   // 4,194,304  : fp32 encoder state
static const size_t OFF_XB  = 16777216ull;   // 2,097,152  : bf16 copy of X
static const size_t OFF_E   = 18874368ull;   // 6,291,456  : QKVb bf16 8192x1536, later AG2 fp32 8192x512
static const size_t OFF_VT  = 25165824ull;   // 2,097,152  : Vtb bf16 [16][64][4096]
static const size_t OFF_CTB = 27262976ull;   // 2,097,152  : CTb bf16 8192x512
static const size_t OFF_W1B = 29360128ull;   // 327,680
static const size_t OFF_IPB = 29687808ull;   // 393,216
static const size_t OFF_OPB = 30081024ull;   // 131,072
static const size_t OFF_F1B = 30212096ull;   // 524,288
static const size_t OFF_F2B = 30736384ull;   // 524,288
static const size_t OFF_W2B = 31260672ull;   // 131,072
static const size_t OFF_ME  = 31391744ull;   // 16,384
static const size_t OFF_DG  = 31408128ull;   // 16,384
static const size_t OFF_INT = 31424512ull;   // 164,096 ints (CSR)

// int-region offsets (in ints, from OFF_INT)
#define IH_S1 0
#define IH_D1 4096
#define IH_S2 8192
#define IH_D2 12288
#define IO_F1 16384
#define IO_F2 20608
#define IC_1  24832
#define IC_2  28928
#define IE_1  33024
#define IE_2  98560

__device__ __forceinline__ u16 f2b(float x) {
    u32 u = __float_as_uint(x);
    return (u16)((u + 0x7fffu + ((u >> 16) & 1u)) >> 16);
}

// ---------------- CSR build ----------------
__global__ __launch_bounds__(256) void k_hist(const int* __restrict__ s1, const int* __restrict__ d1,
                                              const int* __restrict__ s2, const int* __restrict__ d2,
                                              int* __restrict__ I)
{
    int e = blockIdx.x * 256 + threadIdx.x;
    if (e < EE) {
        atomicAdd(&I[IH_S1 + s1[e]], 1);
        atomicAdd(&I[IH_D1 + d1[e]], 1);
        atomicAdd(&I[IH_S2 + s2[e]], 1);
        atomicAdd(&I[IH_D2 + d2[e]], 1);
    }
}

__global__ __launch_bounds__(256) void k_deg_fin(const int* __restrict__ I, float* __restrict__ deg)
{
    int i = blockIdx.x * 256 + threadIdx.x;
    if (i < 4 * NN) deg[i] = rsqrtf(fmaxf((float)I[i], 1.0f));
}

// exclusive scan of the dst histogram -> offsets + cursors (one block per graph)
__global__ __launch_bounds__(256) void k_scan(int* __restrict__ I)
{
    int b = blockIdx.x;
    const int* hist = I + (b ? IH_D2 : IH_D1);
    int* offs = I + (b ? IO_F2 : IO_F1);
    int* cur  = I + (b ? IC_2 : IC_1);
    __shared__ int part[256];
    int t = threadIdx.x;
    int base = t * 16;
    int loc[16];
    int s = 0;
#pragma unroll
    for (int i = 0; i < 16; ++i) { loc[i] = s; s += hist[base + i]; }
    part[t] = s;
    __syncthreads();
    if (t == 0) {
        int a = 0;
        for (int i = 0; i < 256; ++i) { int v = part[i]; part[i] = a; a += v; }
        offs[NN] = a;
    }
    __syncthreads();
    int p = part[t];
#pragma unroll
    for (int i = 0; i < 16; ++i) { offs[base + i] = p + loc[i]; cur[base + i] = p + loc[i]; }
}

__global__ __launch_bounds__(256) void k_fill(const int* __restrict__ s1, const int* __restrict__ d1,
                                              const int* __restrict__ s2, const int* __restrict__ d2,
                                              int* __restrict__ I)
{
    int e = blockIdx.x * 256 + threadIdx.x;
    if (e < EE) {
        int p1 = atomicAdd(&I[IC_1 + d1[e]], 1);
        I[IE_1 + p1] = s1[e];
        int p2 = atomicAdd(&I[IC_2 + d2[e]], 1);
        I[IE_2 + p2] = s2[e];
    }
}

// ---------------- fp32 -> bf16 convert (n multiple of 8) ----------------
__global__ __launch_bounds__(256) void k_cvt(const float* __restrict__ src, u16* __restrict__ dst, int n)
{
    int i = (blockIdx.x * 256 + threadIdx.x) * 8;
    if (i >= n) return;
    float4 a = *(const float4*)&src[i];
    float4 b = *(const float4*)&src[i + 4];
    uint4 o;
    o.x = (u32)f2b(a.x) | ((u32)f2b(a.y) << 16);
    o.y = (u32)f2b(a.z) | ((u32)f2b(a.w) << 16);
    o.z = (u32)f2b(b.x) | ((u32)f2b(b.y) << 16);
    o.w = (u32)f2b(b.z) | ((u32)f2b(b.w) << 16);
    *(uint4*)&dst[i] = o;
}

// ---------------- row scale -> bf16 out (stacked 2-graph) ----------------
__global__ __launch_bounds__(256) void k_scale_bf(const float* __restrict__ in1, const float* __restrict__ in2,
                                                  const float* __restrict__ sc1, const float* __restrict__ sc2,
                                                  u16* __restrict__ out, int ncol)
{
    int quads = ncol >> 2;
    long long idx = (long long)blockIdx.x * 256 + threadIdx.x;
    if (idx >= (long long)NS * quads) return;
    int r  = (int)(idx / quads);
    int cq = (int)(idx % quads) * 4;
    const float* in; const float* sc; int rr;
    if (r < NN) { in = in1; sc = sc1; rr = r; } else { in = in2; sc = sc2; rr = r - NN; }
    float4 v = *(const float4*)&in[(size_t)rr * ncol + cq];
    float s = sc[rr];
    uint2 o;
    o.x = (u32)f2b(v.x * s) | ((u32)f2b(v.y * s) << 16);
    o.y = (u32)f2b(v.z * s) | ((u32)f2b(v.w * s) << 16);
    *(uint2*)&out[(size_t)r * ncol + cq] = o;
}

// ---------------- bf16 MFMA GEMM: C[M,N] = A[M,K] @ W[N,K]^T (+bias)(+relu) ----------------
__global__ __launch_bounds__(256) void k_gemm_bf(const u16* __restrict__ A, const u16* __restrict__ W,
                                                 const float* __restrict__ bias, float* __restrict__ Cf,
                                                 u16* __restrict__ Cb, int M, int N, int K, int relu)
{
    __shared__ u16 As[128 * 32];
    __shared__ u16 Bs[128 * 32];
    int t = threadIdx.x;
    int w = t >> 6, L = t & 63;
    int lm = L & 15, lq = L >> 4;
    int wr = w >> 1, wc = w & 1;
    int row0 = blockIdx.y * 128, col0 = blockIdx.x * 128;
    f32x4 acc[4][4];
#pragma unroll
    for (int i = 0; i < 4; ++i)
#pragma unroll
        for (int j = 0; j < 4; ++j) acc[i][j] = (f32x4){0.f, 0.f, 0.f, 0.f};

    int sr = t >> 2;
    int sk = (t & 3) * 8;
    const u16* Ag = &A[(size_t)row0 * K + sk];
    const u16* Wg = &W[(size_t)col0 * K + sk];

    for (int k0 = 0; k0 < K; k0 += 32) {
        uint4 a0 = *(const uint4*)&Ag[(size_t)sr * K + k0];
        uint4 a1 = *(const uint4*)&Ag[(size_t)(sr + 64) * K + k0];
        uint4 b0 = *(const uint4*)&Wg[(size_t)sr * K + k0];
        uint4 b1 = *(const uint4*)&Wg[(size_t)(sr + 64) * K + k0];
        __syncthreads();
        *(uint4*)&As[sr * 32 + sk] = a0;
        *(uint4*)&As[(sr + 64) * 32 + sk] = a1;
        *(uint4*)&Bs[sr * 32 + sk] = b0;
        *(uint4*)&Bs[(sr + 64) * 32 + sk] = b1;
        __syncthreads();
        bf16x8 af[4], bw[4];
#pragma unroll
        for (int i = 0; i < 4; ++i) {
            af[i] = *(const bf16x8*)&As[(wr * 64 + i * 16 + lm) * 32 + lq * 8];
            bw[i] = *(const bf16x8*)&Bs[(wc * 64 + i * 16 + lm) * 32 + lq * 8];
        }
#pragma unroll
        for (int i = 0; i < 4; ++i)
#pragma unroll
            for (int j = 0; j < 4; ++j)
                acc[i][j] = MFMA16(af[i], bw[j], acc[i][j]);
    }

#pragma unroll
    for (int i = 0; i < 4; ++i) {
        int row = row0 + wr * 64 + i * 16 + lq * 4;
#pragma unroll
        for (int j = 0; j < 4; ++j) {
            int col = col0 + wc * 64 + j * 16 + lm;
            float bv = bias ? bias[col] : 0.0f;
#pragma unroll
            for (int r = 0; r < 4; ++r) {
                float v = acc[i][j][r] + bv;
                if (relu) v = fmaxf(v, 0.0f);
                size_t off = (size_t)(row + r) * N + col;
                if (Cb) Cb[off] = f2b(v);
                else    Cf[off] = v;
            }
        }
    }
}

// ---------------- CSR gather + GC finalize: x[r] = relu(sum_in(hp) * din[r] + b) ----------------
__global__ __launch_bounds__(256) void k_gather(const float* __restrict__ hp, const int* __restrict__ I,
                                                const float* __restrict__ din1, const float* __restrict__ din2,
                                                const float* __restrict__ bias,
                                                float* __restrict__ xout, u16* __restrict__ xb)
{
    int r = blockIdx.x, c = threadIdx.x;
    int g = r >> 12, rl = r & (NN - 1);
    const int* off = I + (g ? IO_F2 : IO_F1);
    const int* eid = I + (g ? IE_2 : IE_1);
    int beg = off[rl], end = off[rl + 1];
    const float* base = hp + ((size_t)g << 12) * NHID;
    float a0 = 0.f, a1 = 0.f;
    for (int i = beg; i < end; ++i) {
        const float* row = base + (size_t)eid[i] * NHID;
        a0 += row[c];
        a1 += row[c + 256];
    }
    float s = (g ? din2 : din1)[rl];
    float v0 = fmaxf(fmaf(a0, s, bias[c]), 0.f);
    float v1 = fmaxf(fmaf(a1, s, bias[c + 256]), 0.f);
    size_t o = (size_t)r * NHID;
    xout[o + c] = v0;
    xout[o + c + 256] = v1;
    if (xb) {
        xb[o + c] = f2b(v0);
        xb[o + c + 256] = f2b(v1);
    }
}

// ---------------- V transpose: QKVb v-part -> Vtb[(g*8+h)*64 + d][k] ----------------
__global__ __launch_bounds__(256) void k_vtrans(const u16* __restrict__ qkvb, u16* __restrict__ vtb)
{
    __shared__ u16 tile[64][65];
    int t = threadIdx.x;
    int kt = blockIdx.x, h = blockIdx.y, g = blockIdx.z;
    int k0 = kt * 64;
    size_t gbase = (size_t)g * NN;
#pragma unroll
    for (int p = 0; p < 4; ++p) {
        int kl = p * 16 + (t >> 4);
        int d  = (t & 15) * 4;
        uint2 v = *(const uint2*)&qkvb[(gbase + k0 + kl) * 1536 + 1024 + h * 64 + d];
        tile[kl][d + 0] = (u16)(v.x & 0xffff);
        tile[kl][d + 1] = (u16)(v.x >> 16);
        tile[kl][d + 2] = (u16)(v.y & 0xffff);
        tile[kl][d + 3] = (u16)(v.y >> 16);
    }
    __syncthreads();
#pragma unroll
    for (int p = 0; p < 4; ++p) {
        int dl = p * 16 + (t >> 4);
        int k4 = (t & 15) * 4;
        u16 v0 = tile[k4 + 0][dl];
        u16 v1 = tile[k4 + 1][dl];
        u16 v2 = tile[k4 + 2][dl];
        u16 v3 = tile[k4 + 3][dl];
        uint2 o;
        o.x = (u32)v0 | ((u32)v1 << 16);
        o.y = (u32)v2 | ((u32)v3 << 16);
        *(uint2*)&vtb[((size_t)(g * 8 + h) * 64 + dl) * (size_t)NN + k0 + k4] = o;
    }
}

// ---------------- MFMA flash attention v2 ----------------
// 1 wave/block, 32 q-rows, 32-key tiles. No K/V LDS: MFMA B-frags are 16B
// row-slices loaded directly from global (L2/L3-resident). Deferred-max
// softmax (T13): per-lane partial l, cross-lane max only when __any(ds>8).
__global__ __launch_bounds__(64, 4) void k_attn(const u16* __restrict__ qkv,
                                                const u16* __restrict__ vt,
                                                u16* __restrict__ ctb)
{
    __shared__ u16 Pl[32 * 40];   // P exchange: C-layout rows -> A-frag rows, 80 B rows (2-way max)
    int L = threadIdx.x;
    int lm = L & 15, lq = L >> 4;
    int qt = blockIdx.x, h = blockIdx.y, g = blockIdx.z;
    size_t gbase = (size_t)g * NN;
    int q0 = qt * 32;

    // Q A-frags (row = q within 16, k = d = lq*8 + j)
    bf16x8 qa[2][2];
#pragma unroll
    for (int qg = 0; qg < 2; ++qg) {
        const u16* qp = &qkv[(gbase + q0 + qg * 16 + lm) * 1536 + h * 64 + lq * 8];
        qa[qg][0] = *(const bf16x8*)qp;
        qa[qg][1] = *(const bf16x8*)(qp + 32);
    }
    f32x4 ctx[2][4];
#pragma unroll
    for (int qg = 0; qg < 2; ++qg)
#pragma unroll
        for (int n = 0; n < 4; ++n) ctx[qg][n] = (f32x4){0.f, 0.f, 0.f, 0.f};
    float m[2][4], lsum[2][4];
#pragma unroll
    for (int qg = 0; qg < 2; ++qg)
#pragma unroll
        for (int r = 0; r < 4; ++r) { m[qg][r] = -1e30f; lsum[qg][r] = 0.0f; }

    // K base: row stride 1536; B-frag col = key-in-16 = lm, k = d
    const u16* kbase = &qkv[gbase * 1536 + 512 + h * 64];
    // V^T base: row stride NN; B-frag col = d-in-16 = lm, k = key
    const u16* vbase = &vt[(size_t)(g * 8 + h) * 64 * (size_t)NN];

    for (int t0 = 0; t0 < NN; t0 += 32) {
        // direct-global B-frags
        bf16x8 kb[2][2], vb[4];
#pragma unroll
        for (int kc = 0; kc < 2; ++kc) {
            const u16* kp = &kbase[(size_t)(t0 + kc * 16 + lm) * 1536 + lq * 8];
            kb[kc][0] = *(const bf16x8*)kp;
            kb[kc][1] = *(const bf16x8*)(kp + 32);
        }
#pragma unroll
        for (int n = 0; n < 4; ++n)
            vb[n] = *(const bf16x8*)&vbase[(size_t)(n * 16 + lm) * NN + t0 + lq * 8];

        // QK^T: S C-layout row = q (lq*4+r), col = key (kc*16+lm)
        f32x4 s[2][2];
        __builtin_amdgcn_s_setprio(1);
#pragma unroll
        for (int kc = 0; kc < 2; ++kc)
#pragma unroll
            for (int qg = 0; qg < 2; ++qg) {
                f32x4 z = (f32x4){0.f, 0.f, 0.f, 0.f};
                z = MFMA16(qa[qg][0], kb[kc][0], z);
                z = MFMA16(qa[qg][1], kb[kc][1], z);
                s[qg][kc] = z * 0.125f;
            }
        __builtin_amdgcn_s_setprio(0);

        // deferred-max check
        float dmax = -1e30f;
#pragma unroll
        for (int qg = 0; qg < 2; ++qg)
#pragma unroll
            for (int r = 0; r < 4; ++r)
                dmax = fmaxf(dmax, fmaxf(s[qg][0][r], s[qg][1][r]) - m[qg][r]);
        if (__any(dmax > 8.0f)) {
            // slow path: full cross-lane max + rescale
#pragma unroll
            for (int qg = 0; qg < 2; ++qg)
#pragma unroll
                for (int r = 0; r < 4; ++r) {
                    float mr = fmaxf(s[qg][0][r], s[qg][1][r]);
                    mr = fmaxf(mr, __shfl_xor(mr, 1));
                    mr = fmaxf(mr, __shfl_xor(mr, 2));
                    mr = fmaxf(mr, __shfl_xor(mr, 4));
                    mr = fmaxf(mr, __shfl_xor(mr, 8));
                    float mn = fmaxf(m[qg][r], mr);
                    float corr = __expf(m[qg][r] - mn);
                    m[qg][r] = mn;
                    lsum[qg][r] *= corr;
#pragma unroll
                    for (int n = 0; n < 4; ++n) ctx[qg][n][r] *= corr;
                }
        }
        // common path: exp, per-lane l partial, P -> LDS (bf16)
#pragma unroll
        for (int qg = 0; qg < 2; ++qg)
#pragma unroll
            for (int r = 0; r < 4; ++r) {
                float p0 = __expf(s[qg][0][r] - m[qg][r]);
                float p1 = __expf(s[qg][1][r] - m[qg][r]);
                lsum[qg][r] += p0 + p1;
                int row = qg * 16 + lq * 4 + r;
                Pl[row * 40 + lm] = f2b(p0);
                Pl[row * 40 + 16 + lm] = f2b(p1);
            }

        // PV: A = P (row = q = lm, k = key = lq*8+j), B = V^T
        __builtin_amdgcn_s_setprio(1);
#pragma unroll
        for (int qg = 0; qg < 2; ++qg) {
            bf16x8 pa = *(const bf16x8*)&Pl[(qg * 16 + lm) * 40 + lq * 8];
#pragma unroll
            for (int n = 0; n < 4; ++n)
                ctx[qg][n] = MFMA16(pa, vb[n], ctx[qg][n]);
        }
        __builtin_amdgcn_s_setprio(0);
    }

    // epilogue: reduce per-lane l partials across the 16 key-lanes, normalize
#pragma unroll
    for (int qg = 0; qg < 2; ++qg) {
        float inv[4];
#pragma unroll
        for (int r = 0; r < 4; ++r) {
            float lr = lsum[qg][r];
            lr += __shfl_xor(lr, 1);
            lr += __shfl_xor(lr, 2);
            lr += __shfl_xor(lr, 4);
            lr += __shfl_xor(lr, 8);
            inv[r] = 1.0f / lr;
        }
#pragma unroll
        for (int n = 0; n < 4; ++n)
#pragma unroll
            for (int r = 0; r < 4; ++r) {
                int row = q0 + qg * 16 + lq * 4 + r;
                int col = h * 64 + n * 16 + lm;
                ctb[(gbase + row) * NHID + col] = f2b(ctx[qg][n][r] * inv[r]);
            }
    }
}

// ---------------- fused residual-add + LayerNorm + bf16 copy ----------------
__global__ __launch_bounds__(256) void k_add_ln(float* __restrict__ x, const float* __restrict__ y,
                                                const float* __restrict__ g, const float* __restrict__ bb,
                                                u16* __restrict__ xb)
{
    int r = blockIdx.x, tid = threadIdx.x;
    int c = tid * 2;
    float2 xv = *(float2*)&x[(size_t)r * NHID + c];
    float2 yv = *(const float2*)&y[(size_t)r * NHID + c];
    float a0 = xv.x + yv.x, a1 = xv.y + yv.y;
    float s = a0 + a1;
    float qs = a0 * a0 + a1 * a1;
#pragma unroll
    for (int off = 32; off > 0; off >>= 1) {
        s  += __shfl_xor(s, off);
        qs += __shfl_xor(qs, off);
    }
    __shared__ float ss[4], qq[4];
    int w = tid >> 6;
    if ((tid & 63) == 0) { ss[w] = s; qq[w] = qs; }
    __syncthreads();
    s  = ss[0] + ss[1] + ss[2] + ss[3];
    qs = qq[0] + qq[1] + qq[2] + qq[3];
    float mu  = s * (1.0f / NHID);
    float var = qs * (1.0f / NHID) - mu * mu;
    float rs = rsqrtf(var + 1e-5f);
    float2 gv = *(const float2*)&g[c];
    float2 bv = *(const float2*)&bb[c];
    float o0 = (a0 - mu) * rs * gv.x + bv.x;
    float o1 = (a1 - mu) * rs * gv.y + bv.y;
    *(float2*)&x[(size_t)r * NHID + c] = make_float2(o0, o1);
    u32 o = (u32)f2b(o0) | ((u32)f2b(o1) << 16);
    *(u32*)&xb[(size_t)r * NHID + c] = o;
}

// ---------------- per-segment mean (contiguous 256-row segments) ----------------
__global__ __launch_bounds__(512) void k_seg_mean(const float* __restrict__ h, float* __restrict__ means)
{
    int b = blockIdx.x;
    int st = blockIdx.y;
    int col = threadIdx.x;
    const float* hp = &h[((size_t)st * NN + (size_t)b * 256) * NHID + col];
    float acc = 0.0f;
    for (int i = 0; i < 256; ++i) acc += hp[(size_t)i * NHID];
    means[((size_t)st * 16 + b) * NHID + col] = acc * (1.0f / 256.0f);
}

// ---------------- MLP head + softmax (16 blocks, one per segment) ----------------
__global__ __launch_bounds__(256) void k_head(const float* __restrict__ means,
                                              const float* __restrict__ l1w, const float* __restrict__ l1b,
                                              const float* __restrict__ l2w, const float* __restrict__ l2b,
                                              const float* __restrict__ l3w, const float* __restrict__ l3b,
                                              float* __restrict__ out)
{
    __shared__ float hg[512];
    __shared__ float t1[512];
    __shared__ float t2[128];
    int b = blockIdx.x;
    int t = threadIdx.x;
    hg[t]       = means[b * 512 + t]       * means[(16 + b) * 512 + t];
    hg[t + 256] = means[b * 512 + t + 256] * means[(16 + b) * 512 + t + 256];
    __syncthreads();
#pragma unroll
    for (int o = t; o < 512; o += 256) {
        const float* wr = &l1w[(size_t)o * 512];
        float acc = l1b[o];
        for (int k = 0; k < 512; k += 4) {
            float4 w = *(const float4*)&wr[k];
            acc = fmaf(hg[k], w.x, acc);
            acc = fmaf(hg[k + 1], w.y, acc);
            acc = fmaf(hg[k + 2], w.z, acc);
            acc = fmaf(hg[k + 3], w.w, acc);
        }
        t1[o] = acc;
    }
    __syncthreads();
    if (t < 128) {
        const float* wr = &l2w[(size_t)t * 512];
        float acc = l2b[t];
        for (int k = 0; k < 512; k += 4) {
            float4 w = *(const float4*)&wr[k];
            acc = fmaf(t1[k], w.x, acc);
            acc = fmaf(t1[k + 1], w.y, acc);
            acc = fmaf(t1[k + 2], w.z, acc);
            acc = fmaf(t1[k + 3], w.w, acc);
        }
        t2[t] = acc;
    }
    __syncthreads();
    if (t < 64) {
        float p0 = t2[t] * l3w[t] + t2[t + 64] * l3w[t + 64];
        float p1 = t2[t] * l3w[128 + t] + t2[t + 64] * l3w[128 + t + 64];
#pragma unroll
        for (int off = 32; off > 0; off >>= 1) {
            p0 += __shfl_xor(p0, off);
            p1 += __shfl_xor(p1, off);
        }
        if (t == 0) {
            float v0 = p0 + l3b[0], v1 = p1 + l3b[1];
            float mx = fmaxf(v0, v1);
            float e0 = __expf(v0 - mx), e1 = __expf(v1 - mx);
            float inv = 1.0f / (e0 + e1);
            out[b * 2 + 0] = e0 * inv;
            out[b * 2 + 1] = e1 * inv;
        }
    }
}

// ---------------- launch ----------------
extern "C" void kernel_launch(void* const* d_in, const int* in_sizes, int n_in,
                              void* d_out, int out_size, void* d_ws, size_t ws_size,
                              hipStream_t stream)
{
    const float* fea1 = (const float*)d_in[0];
    const float* fea2 = (const float*)d_in[1];
    const int* src1 = (const int*)d_in[2];
    const int* dst1 = (const int*)d_in[3];
    const int* src2 = (const int*)d_in[4];
    const int* dst2 = (const int*)d_in[5];
    const float* W1 = (const float*)d_in[9];
    const float* b1 = (const float*)d_in[10];
    const float* W2 = (const float*)d_in[11];
    const float* b2 = (const float*)d_in[12];
    const float* in_proj_w = (const float*)d_in[13];
    const float* in_proj_b = (const float*)d_in[14];
    const float* out_proj_w = (const float*)d_in[15];
    const float* out_proj_b = (const float*)d_in[16];
    const float* ln1_g = (const float*)d_in[17];
    const float* ln1_b = (const float*)d_in[18];
    const float* ln2_g = (const float*)d_in[19];
    const float* ln2_b = (const float*)d_in[20];
    const float* ff1_w = (const float*)d_in[21];
    const float* ff1_b = (const float*)d_in[22];
    const float* ff2_w = (const float*)d_in[23];
    const float* ff2_b = (const float*)d_in[24];
    const float* l1_w = (const float*)d_in[25];
    const float* l1_b = (const float*)d_in[26];
    const float* l2_w = (const float*)d_in[27];
    const float* l2_b = (const float*)d_in[28];
    const float* l3_w = (const float*)d_in[29];
    const float* l3_b = (const float*)d_in[30];

    float* ws = (float*)d_ws;
    u16*  Ab   = (u16*)(ws + OFF_A);
    float* HP  = ws + OFF_HP;
    float* X   = ws + OFF_X;
    u16*  Xb   = (u16*)(ws + OFF_XB);
    u16*  QKVb = (u16*)(ws + OFF_E);
    float* AG2 = ws + OFF_E;
    u16*  Vtb  = (u16*)(ws + OFF_VT);
    u16*  CTb  = (u16*)(ws + OFF_CTB);
    u16*  W1b  = (u16*)(ws + OFF_W1B);
    u16*  IPb  = (u16*)(ws + OFF_IPB);
    u16*  OPb  = (u16*)(ws + OFF_OPB);
    u16*  F1b  = (u16*)(ws + OFF_F1B);
    u16*  F2b  = (u16*)(ws + OFF_F2B);
    u16*  W2b  = (u16*)(ws + OFF_W2B);
    float* ME  = ws + OFF_ME;
    float* DG  = ws + OFF_DG;
    int*   I   = (int*)(ws + OFF_INT);
    float* dout1 = DG;
    float* din1  = DG + NN;
    float* dout2 = DG + 2 * NN;
    float* din2  = DG + 3 * NN;

    // zero the 4 histograms (64 KB); everything else is fully overwritten
    hipMemsetAsync(I, 0, 4 * NN * sizeof(int), stream);

    // CSR build + degrees
    k_hist<<<EE / 256, 256, 0, stream>>>(src1, dst1, src2, dst2, I);
    k_deg_fin<<<(4 * NN) / 256, 256, 0, stream>>>(I, DG);
    k_scan<<<2, 256, 0, stream>>>(I);
    k_fill<<<EE / 256, 256, 0, stream>>>(src1, dst1, src2, dst2, I);

    // weight conversions
    k_cvt<<<(NHID * NFEAT / 8 + 255) / 256, 256, 0, stream>>>(W1, W1b, NHID * NFEAT);
    k_cvt<<<(3 * NHID * NHID / 8 + 255) / 256, 256, 0, stream>>>(in_proj_w, IPb, 3 * NHID * NHID);
    k_cvt<<<(NHID * NHID / 8 + 255) / 256, 256, 0, stream>>>(out_proj_w, OPb, NHID * NHID);
    k_cvt<<<(DFF * NHID / 8 + 255) / 256, 256, 0, stream>>>(ff1_w, F1b, DFF * NHID);
    k_cvt<<<(NHID * DFF / 8 + 255) / 256, 256, 0, stream>>>(ff2_w, F2b, NHID * DFF);
    k_cvt<<<(NHID * NHID / 8 + 255) / 256, 256, 0, stream>>>(W2, W2b, NHID * NHID);

    // GC1
    {
        long long tq = (long long)NS * (NFEAT / 4);
        k_scale_bf<<<(int)((tq + 255) / 256), 256, 0, stream>>>(fea1, fea2, dout1, dout2, Ab, NFEAT);
    }
    k_gemm_bf<<<dim3(NHID / 128, NS / 128), 256, 0, stream>>>(Ab, W1b, nullptr, HP, nullptr, NS, NHID, NFEAT, 0);
    k_gather<<<NS, 256, 0, stream>>>(HP, I, din1, din2, b1, X, Xb);

    // encoder
    k_gemm_bf<<<dim3(1536 / 128, NS / 128), 256, 0, stream>>>(Xb, IPb, in_proj_b, nullptr, QKVb, NS, 1536, NHID, 0);
    k_vtrans<<<dim3(NN / 64, 8, 2), 256, 0, stream>>>(QKVb, Vtb);
    k_attn<<<dim3(NN / 32, 8, 2), 64, 0, stream>>>(QKVb, Vtb, CTb);
    k_gemm_bf<<<dim3(NHID / 128, NS / 128), 256, 0, stream>>>(CTb, OPb, out_proj_b, HP, nullptr, NS, NHID, NHID, 0);
    k_add_ln<<<NS, 256, 0, stream>>>(X, HP, ln1_g, ln1_b, Xb);
    k_gemm_bf<<<dim3(DFF / 128, NS / 128), 256, 0, stream>>>(Xb, F1b, ff1_b, nullptr, Ab, NS, DFF, NHID, 1);
    k_gemm_bf<<<dim3(NHID / 128, NS / 128), 256, 0, stream>>>(Ab, F2b, ff2_b, HP, nullptr, NS, NHID, DFF, 0);
    k_add_ln<<<NS, 256, 0, stream>>>(X, HP, ln2_g, ln2_b, Xb);

    // GC2
    {
        long long tq = (long long)NS * (NHID / 4);
        k_scale_bf<<<(int)((tq + 255) / 256), 256, 0, stream>>>(X, X + (size_t)NN * NHID, dout1, dout2, Ab, NHID);
    }
    k_gemm_bf<<<dim3(NHID / 128, NS / 128), 256, 0, stream>>>(Ab, W2b, nullptr, HP, nullptr, NS, NHID, NHID, 0);
    k_gather<<<NS, 256, 0, stream>>>(HP, I, din1, din2, b2, AG2, nullptr);

    // readout
    k_seg_mean<<<dim3(16, 2), 512, 0, stream>>>(AG2, ME);
    k_head<<<16, 256, 0, stream>>>(ME, l1_w, l1_b, l2_w, l2_b, l3_w, l3_b, (float*)d_out);
}